// Round 3
// 4272.630 us; speedup vs baseline: 1.0058x; 1.0058x over previous
//
#include <hip/hip_runtime.h>

// Problem constants
#define Tt 256

// ws layout in unsigned shorts (fp16 bit patterns / ints for flags):
//  flags : ints [0..256) arrival flags (4B packed)      [first 1KB of 32KB region]
//  h0 [2 parity][64 g][128 row][8]  fp16 frag-major     [256 KB]   (g = col>>3)
//  h1 same                                              [256 KB]
//  w0lo [64 cg][104 kg][32 n][8]  fp16, lo=(w-fp16(w))*1024, block-private frag-lane order
//  w1lo [64 cg][128 kg][32 n][8]
// total = 4,079,616 shorts = 8,159,232 B (byte-identical to the R5..R7 proven budget)
#define FLAGS_SHORTS 16384
#define H0OFF  16384
#define H1OFF  (H0OFF + 2*64*128*8)
#define W0LOFF (H1OFF + 2*64*128*8)
#define W1LOFF (W0LOFF + 64*104*32*8)
#define HPAR   (64*128*8)            // u16 per parity plane = 65536

typedef _Float16 h8 __attribute__((ext_vector_type(8)));
typedef float    f4 __attribute__((ext_vector_type(4)));
typedef unsigned long long ull;
typedef unsigned short u16;

#define MFMA __builtin_amdgcn_mfma_f32_16x16x32_f16
#define LOSC (1.0f/1024.0f)

__device__ inline u16 h_bits(float f){ union{_Float16 h; u16 s;} u; u.h=(_Float16)f; return u.s; }
__device__ inline float bits_f(u16 s){ union{u16 s2; _Float16 h;} u; u.s2=s; return (float)u.h; }
__device__ inline float sigm(float x){ return 1.f/(1.f+expf(-x)); }

// Coherent 16B A-fragment load: two relaxed agent-scope 8B atomic loads (IF$-served, proven R2..R7).
__device__ inline h8 ldH(const u16* p){
    union{ ull u[2]; h8 v; } t;
    t.u[0]=__hip_atomic_load((const ull*)p,    __ATOMIC_RELAXED, __HIP_MEMORY_SCOPE_AGENT);
    t.u[1]=__hip_atomic_load((const ull*)(p+4),__ATOMIC_RELAXED, __HIP_MEMORY_SCOPE_AGENT);
    return t.v;
}

// ---------------- pre-pack W lo-planes (fp16, x1024), [cg][kg][n 0..32)[8] ----------------
__global__ __launch_bounds__(256) void prepack(const float* __restrict__ W0,
                                               const float* __restrict__ W1,
                                               u16* __restrict__ ws) {
    int idx = blockIdx.x * 256 + threadIdx.x;
    const int NW0 = 64 * 104 * 32;
    if (idx < NW0) {
        int cg  = idx / (104 * 32);
        int rem = idx - cg * (104 * 32);
        int kg = rem >> 5, n = rem & 31;
        int col = ((n >> 3) << 9) + (cg << 3) + (n & 7);
        u16 t[8];
#pragma unroll
        for (int j = 0; j < 8; j++) {
            int k = kg * 8 + j;
            float w = 0.f;
            if (k < 300) w = W0[k * 2048 + col];
            else if (k >= 320) w = W0[(k - 20) * 2048 + col];
            _Float16 wh = (_Float16)w;
            t[j] = h_bits((w - (float)wh) * 1024.0f);
        }
#pragma unroll
        for (int j = 0; j < 8; j++) ws[W0LOFF + (size_t)idx * 8 + j] = t[j];
    } else {
        int i2 = idx - NW0;
        if (i2 < 64 * 128 * 32) {
            int cg  = i2 >> 12;           // / (128*32)
            int rem = i2 & 4095;
            int kg = rem >> 5, n = rem & 31;
            int col = ((n >> 3) << 9) + (cg << 3) + (n & 7);
            u16 t[8];
#pragma unroll
            for (int j = 0; j < 8; j++) {
                float w = W1[(kg * 8 + j) * 2048 + col];
                _Float16 wh = (_Float16)w;
                t[j] = h_bits((w - (float)wh) * 1024.0f);
            }
#pragma unroll
            for (int j = 0; j < 8; j++) ws[W1LOFF + (size_t)i2 * 8 + j] = t[j];
        }
    }
}

// Fence-free split barrier — EXACT R7-proven structure (all threads poll packed flags).
// 256 blocks: thread tid polls flags[tid]. Initial poison (0xAAAAAAAA<0) needs no init.
// R10 change (ONLY delta vs the proven R0 binary): s_sleep(1) -> s_sleep(4) in the poll
// loop, cutting the chip-wide poll-transaction storm on the 8 flag cache lines ~4x so
// flag stores and h-data reads get coherent-fabric service. Worst-case added detect
// latency 256 clk (~0.1 us) per barrier, negligible vs the 16.5 us phase.
__device__ inline void barrier_arrive(int* __restrict__ flags, int tid, int bid, int target) {
    __builtin_amdgcn_s_waitcnt(0);
    __syncthreads();
    if (tid == 0)
        __hip_atomic_store(flags + bid, target, __ATOMIC_RELAXED, __HIP_MEMORY_SCOPE_AGENT);
}
__device__ inline void barrier_wait(int* __restrict__ flags, int tid, int target) {
    while (__hip_atomic_load(flags + tid, __ATOMIC_RELAXED, __HIP_MEMORY_SCOPE_AGENT) < target)
        __builtin_amdgcn_s_sleep(4);
    __syncthreads();
}

struct X4 { f4 h0, l0, h1, l1; };

// ---------------- persistent cooperative LSTM kernel ----------------
// grid 256 x 256 (1 block/CU): bid = inner*2 + lyr.
//   lyr = bid&1 : 0 -> layer-0 duties, 1 -> layer-1 duties (R7 split, proven)
//   inner = bid>>1 in [0,128): bq = inner>>6 (64-row batch half), cg = inner&63 (8 h-cols
//   -> 32 gate-cols). Each wave loads ONE A-frag per kt and reuses it for BOTH n-tiles,
//   halving the per-h-element consumer count (24 MB/phase coherent vs R7's 48).
// NOTE (R8/R9 lesson): hoisting the ldH loads into af[] arrays breaks correctness
// deterministically (compiler migrates naked relaxed atomic loads across the relaxed
// flag poll). The interleaved load structure below is load-bearing — do not reorder.
__global__ __launch_bounds__(256, 1) void lstm_coop(
    const int* __restrict__ x, const float* __restrict__ emb,
    const float* __restrict__ W0, const float* __restrict__ b0,
    const float* __restrict__ W1, const float* __restrict__ b1,
    const float* __restrict__ Wd, const float* __restrict__ bd,
    float* __restrict__ out, u16* __restrict__ ws) {

    const int tid  = threadIdx.x;
    const int lane = tid & 63;
    const int wave = tid >> 6;        // 0..3 : m-tile (16 rows each)
    const int quad = lane >> 4;       // 0..3 : k-chunk of 8 in frags
    const int fm   = lane & 15;       // A: m, B: n, C/D: col
    const int bid  = blockIdx.x;
    const int lyr  = bid & 1;
    const int inner= bid >> 1;
    const int bq   = inner >> 6;
    const int cg   = inner & 63;

    __shared__ u16   whi[128 * 32 * 8];   // 65,536 B (lyr0 uses first 104*32*8)
    __shared__ float csm[64 * 33];        //  8,448 B  (73,984 B total -> 2 blocks/CU validates)

    int* flags = (int*)ws;
    const u16* w0lo = ws + W0LOFF + (size_t)cg * 104 * 32 * 8;   // block-private slice
    const u16* w1lo = ws + W1LOFF + (size_t)cg * 128 * 32 * 8;

    // --- fill LDS hi-plane (fp16) of this block's layer & 32 gate columns, layout [kg][n][8] ---
    if (lyr == 0) {
        for (int i = tid; i < 104 * 32 * 8; i += 256) {
            int kg = i >> 8; int rem = i & 255; int n = rem >> 3; int j = rem & 7;
            int k = kg * 8 + j;
            int col = ((n >> 3) << 9) + (cg << 3) + (n & 7);
            float w = 0.f;
            if (k < 300) w = W0[k * 2048 + col];
            else if (k >= 320) w = W0[(k - 20) * 2048 + col];
            whi[i] = h_bits(w);
        }
    } else {
        for (int i = tid; i < 128 * 32 * 8; i += 256) {
            int kg = i >> 8; int rem = i & 255; int n = rem >> 3; int j = rem & 7;
            int k = kg * 8 + j;
            int col = ((n >> 3) << 9) + (cg << 3) + (n & 7);
            whi[i] = h_bits(W1[k * 2048 + col]);
        }
    }

    // h addressing (frag-major, unchanged layout): plane u16 index = cg*1024 + row*8 + c, c in [0,8)
    // --- zero-init own slice: lyr0 -> h0 parity 0 ; lyr1 -> h1 parity 1 (64 rows x 8 cols) ---
    {
        int row = bq * 64 + (tid >> 2);
        int c = (tid & 3) << 1;
        unsigned int* pz = (unsigned int*)(ws + (lyr ? H1OFF + 1 * HPAR : H0OFF + 0 * HPAR)
                                           + cg * 1024 + row * 8 + c);
        __hip_atomic_store(pz, 0u, __ATOMIC_RELAXED, __HIP_MEMORY_SCOPE_AGENT);
    }

    const int arow = bq * 64 + wave * 16 + fm;   // A-frag row (batch index)
    // act cell: 2 cells per thread: (row m, h-cols hc and hc+4)
    const int actm   = tid >> 2;
    const int acthc  = tid & 3;
    const int actrow = bq * 64 + actm;
    const int ca = (cg << 3) + acthc;        // global h-col of cell A
    const int cb = ca + 4;                   // cell B

    const float biA = lyr ? b1[ca]        : b0[ca];
    const float bjA = lyr ? b1[512 + ca]  : b0[512 + ca];
    const float bfA = lyr ? b1[1024 + ca] : b0[1024 + ca];
    const float boA = lyr ? b1[1536 + ca] : b0[1536 + ca];
    const float biB = lyr ? b1[cb]        : b0[cb];
    const float bjB = lyr ? b1[512 + cb]  : b0[512 + cb];
    const float bfB = lyr ? b1[1024 + cb] : b0[1024 + cb];
    const float boB = lyr ? b1[1536 + cb] : b0[1536 + cb];

    float csA = 0.f, csB = 0.f;

    // x-part GEMM of layer 0 for timestep pp (kt 0..9, both n-tiles); lyr0 only,
    // runs inside the barrier arrive->wait window.
    auto xgemm = [&](int pp) -> X4 {
        X4 a; a.h0 = (f4){0,0,0,0}; a.l0 = a.h0; a.h1 = a.h0; a.l1 = a.h0;
        int xi = x[arow * Tt + pp];
        xi = (xi < 0) ? 0 : ((xi >= 50000) ? 49999 : xi);
        const float* embrow = emb + (size_t)xi * 300;
#pragma unroll
        for (int kt = 0; kt < 10; kt++) {
            int kbase = kt * 32 + quad * 8;
            h8 af;
            if (kt < 9) {
                f4 u0 = *(const f4*)(embrow + kbase);
                f4 u1 = *(const f4*)(embrow + kbase + 4);
#pragma unroll
                for (int e = 0; e < 4; e++) { af[e] = (_Float16)u0[e]; af[4+e] = (_Float16)u1[e]; }
            } else {
#pragma unroll
                for (int e = 0; e < 8; e++) { int kk = kbase + e; af[e] = (_Float16)((kk < 300) ? embrow[kk] : 0.f); }
            }
            int kb = (kt * 4 + quad) * 32;
            a.h0 = MFMA(af, *(const h8*)&whi[(kb + fm) * 8],        a.h0, 0,0,0);
            a.l0 = MFMA(af, *(const h8*)(w0lo + (kb + fm) * 8),      a.l0, 0,0,0);
            a.h1 = MFMA(af, *(const h8*)&whi[(kb + 16 + fm) * 8],   a.h1, 0,0,0);
            a.l1 = MFMA(af, *(const h8*)(w0lo + (kb + 16 + fm) * 8), a.l1, 0,0,0);
        }
        return a;
    };

    X4 accx;
    barrier_arrive(flags, tid, bid, 1);
    if (lyr == 0) accx = xgemm(0);
    barrier_wait(flags, tid, 1);

    for (int p = 0; p <= Tt; ++p) {
        const int par = p & 1, wpar = 1 - par;

        if (lyr == 1) {
            if (p >= 1) {   // ---- layer 1 for t=p-1 : g1 = [h0(p-1) | h1(p-2)] @ W1 ----
                f4 aH0 = (f4){0,0,0,0}, aL0 = aH0, aH1 = aH0, aL1 = aH0;
                const u16* h0p = ws + H0OFF + par * HPAR + arow * 8;
                const u16* h1p = ws + H1OFF + par * HPAR + arow * 8;
#pragma unroll 8
                for (int kt = 0; kt < 32; kt++) {
                    h8 af = (kt < 16) ? ldH(h0p + (kt * 4 + quad) * 1024)
                                      : ldH(h1p + ((kt - 16) * 4 + quad) * 1024);
                    int kb = (kt * 4 + quad) * 32;
                    aH0 = MFMA(af, *(const h8*)&whi[(kb + fm) * 8],        aH0, 0,0,0);
                    aL0 = MFMA(af, *(const h8*)(w1lo + (kb + fm) * 8),      aL0, 0,0,0);
                    aH1 = MFMA(af, *(const h8*)&whi[(kb + 16 + fm) * 8],   aH1, 0,0,0);
                    aL1 = MFMA(af, *(const h8*)(w1lo + (kb + 16 + fm) * 8), aL1, 0,0,0);
                }
#pragma unroll
                for (int r = 0; r < 4; r++) {
                    csm[(wave * 16 + quad * 4 + r) * 33 + fm]      = aH0[r] + aL0[r] * LOSC;
                    csm[(wave * 16 + quad * 4 + r) * 33 + 16 + fm] = aH1[r] + aL1[r] * LOSC;
                }
                __syncthreads();
                {   // gates: in-block col = gate*8 + hc
                    float giA = csm[actm * 33 + acthc]           + biA;
                    float gjA = csm[actm * 33 + 8 + acthc]       + bjA;
                    float gfA = csm[actm * 33 + 16 + acthc]      + bfA;
                    float goA = csm[actm * 33 + 24 + acthc]      + boA;
                    float giB = csm[actm * 33 + 4 + acthc]       + biB;
                    float gjB = csm[actm * 33 + 12 + acthc]      + bjB;
                    float gfB = csm[actm * 33 + 20 + acthc]      + bfB;
                    float goB = csm[actm * 33 + 28 + acthc]      + boB;
                    csA = csA * sigm(gfA + 1.f) + sigm(giA) * tanhf(gjA);
                    csB = csB * sigm(gfB + 1.f) + sigm(giB) * tanhf(gjB);
                    float hA = tanhf(csA) * sigm(goA);
                    float hB = tanhf(csB) * sigm(goB);
                    u16 ha = h_bits(hA), hb = h_bits(hB);
                    unsigned int pa = (unsigned int)ha | (((unsigned int)(u16)__shfl_xor((int)ha, 1, 64)) << 16);
                    unsigned int pb = (unsigned int)hb | (((unsigned int)(u16)__shfl_xor((int)hb, 1, 64)) << 16);
                    if (!(acthc & 1)) {
                        u16* base = ws + H1OFF + wpar * HPAR + cg * 1024 + actrow * 8;
                        __hip_atomic_store((unsigned int*)(base + acthc),     pa, __ATOMIC_RELAXED, __HIP_MEMORY_SCOPE_AGENT);
                        __hip_atomic_store((unsigned int*)(base + 4 + acthc), pb, __ATOMIC_RELAXED, __HIP_MEMORY_SCOPE_AGENT);
                    }
                }
            }
        } else {
            if (p < Tt) {   // ---- layer 0 h-part for t=p (x-part already in accx) ----
                f4 aH0 = accx.h0, aL0 = accx.l0, aH1 = accx.h1, aL1 = accx.l1;
                const u16* h0p = ws + H0OFF + par * HPAR + arow * 8;
#pragma unroll 8
                for (int kt = 10; kt < 26; kt++) {
                    h8 af = ldH(h0p + (kt * 4 + quad - 40) * 1024);
                    int kb = (kt * 4 + quad) * 32;
                    aH0 = MFMA(af, *(const h8*)&whi[(kb + fm) * 8],        aH0, 0,0,0);
                    aL0 = MFMA(af, *(const h8*)(w0lo + (kb + fm) * 8),      aL0, 0,0,0);
                    aH1 = MFMA(af, *(const h8*)&whi[(kb + 16 + fm) * 8],   aH1, 0,0,0);
                    aL1 = MFMA(af, *(const h8*)(w0lo + (kb + 16 + fm) * 8), aL1, 0,0,0);
                }
#pragma unroll
                for (int r = 0; r < 4; r++) {
                    csm[(wave * 16 + quad * 4 + r) * 33 + fm]      = aH0[r] + aL0[r] * LOSC;
                    csm[(wave * 16 + quad * 4 + r) * 33 + 16 + fm] = aH1[r] + aL1[r] * LOSC;
                }
                __syncthreads();
                {
                    float giA = csm[actm * 33 + acthc]           + biA;
                    float gjA = csm[actm * 33 + 8 + acthc]       + bjA;
                    float gfA = csm[actm * 33 + 16 + acthc]      + bfA;
                    float goA = csm[actm * 33 + 24 + acthc]      + boA;
                    float giB = csm[actm * 33 + 4 + acthc]       + biB;
                    float gjB = csm[actm * 33 + 12 + acthc]      + bjB;
                    float gfB = csm[actm * 33 + 20 + acthc]      + bfB;
                    float goB = csm[actm * 33 + 28 + acthc]      + boB;
                    csA = csA * sigm(gfA + 1.f) + sigm(giA) * tanhf(gjA);
                    csB = csB * sigm(gfB + 1.f) + sigm(giB) * tanhf(gjB);
                    float hA = tanhf(csA) * sigm(goA);
                    float hB = tanhf(csB) * sigm(goB);
                    u16 ha = h_bits(hA), hb = h_bits(hB);
                    unsigned int pa = (unsigned int)ha | (((unsigned int)(u16)__shfl_xor((int)ha, 1, 64)) << 16);
                    unsigned int pb = (unsigned int)hb | (((unsigned int)(u16)__shfl_xor((int)hb, 1, 64)) << 16);
                    if (!(acthc & 1)) {
                        u16* base = ws + H0OFF + wpar * HPAR + cg * 1024 + actrow * 8;
                        __hip_atomic_store((unsigned int*)(base + acthc),     pa, __ATOMIC_RELAXED, __HIP_MEMORY_SCOPE_AGENT);
                        __hip_atomic_store((unsigned int*)(base + 4 + acthc), pb, __ATOMIC_RELAXED, __HIP_MEMORY_SCOPE_AGENT);
                    }
                }
            }
        }

        barrier_arrive(flags, tid, bid, p + 2);
        if (lyr == 0 && p + 1 < Tt) accx = xgemm(p + 1);
        barrier_wait(flags, tid, p + 2);
    }

    // ---- final logits: h1(T-1) lives in parity 1 (frag-major addressing, unchanged) ----
    if (bid == 0) {
        int b = tid >> 1, jj = tid & 1;
        float sum = bd[jj];
        const u16* hh = ws + H1OFF + 1 * HPAR;
        for (int g = 0; g < 64; g++) {
#pragma unroll
            for (int j4 = 0; j4 < 8; j4 += 4) {
                ull u = __hip_atomic_load((const ull*)(hh + (g * 128 + b) * 8 + j4),
                                          __ATOMIC_RELAXED, __HIP_MEMORY_SCOPE_AGENT);
#pragma unroll
                for (int e = 0; e < 4; e++)
                    sum += bits_f((u16)(u >> (16 * e))) * Wd[(g * 8 + j4 + e) * 2 + jj];
            }
        }
        out[b * 2 + jj] = sum;
    }
}

extern "C" void kernel_launch(void* const* d_in, const int* in_sizes, int n_in,
                              void* d_out, int out_size, void* d_ws, size_t ws_size,
                              hipStream_t stream) {
    const int*   x   = (const int*)d_in[0];
    const float* emb = (const float*)d_in[1];
    const float* W0  = (const float*)d_in[2];
    const float* b0  = (const float*)d_in[3];
    const float* W1  = (const float*)d_in[4];
    const float* b1  = (const float*)d_in[5];
    const float* Wd  = (const float*)d_in[6];
    const float* bd  = (const float*)d_in[7];
    float* out = (float*)d_out;
    u16* ws = (u16*)d_ws;

    hipLaunchKernelGGL(prepack, dim3(1856), dim3(256), 0, stream, W0, W1, ws);

    void* args[] = { (void*)&x, (void*)&emb, (void*)&W0, (void*)&b0, (void*)&W1,
                     (void*)&b1, (void*)&Wd, (void*)&bd, (void*)&out, (void*)&ws };
    hipLaunchCooperativeKernel((void*)lstm_coop, dim3(256), dim3(256), args, 0, stream);
}

// Round 4
// 3229.572 us; speedup vs baseline: 1.3306x; 1.3230x over previous
//
#include <hip/hip_runtime.h>

// Problem constants
#define Tt 256

// ws layout in unsigned shorts (fp16 bit patterns / ints for flags):
//  flags : ints [0..256) arrival flags (4B packed)      [first 1KB of 32KB region]
//  h0 [2 parity][64 g][128 row][8]  fp16 frag-major     [256 KB]   (g = col>>3)
//  h1 same                                              [256 KB]
//  w0lo [64 cg][104 kg][32 n][8]  fp16, lo=(w-fp16(w))*1024, block-private frag-lane order
//  w1lo [64 cg][128 kg][32 n][8]
// total = 4,079,616 shorts = 8,159,232 B (byte-identical to the R5..R7 proven budget)
#define FLAGS_SHORTS 16384
#define H0OFF  16384
#define H1OFF  (H0OFF + 2*64*128*8)
#define W0LOFF (H1OFF + 2*64*128*8)
#define W1LOFF (W0LOFF + 64*104*32*8)
#define HPAR   (64*128*8)            // u16 per parity plane = 65536

typedef _Float16 h8 __attribute__((ext_vector_type(8)));
typedef float    f4 __attribute__((ext_vector_type(4)));
typedef unsigned long long ull;
typedef unsigned short u16;

#define MFMA __builtin_amdgcn_mfma_f32_16x16x32_f16
#define LOSC (1.0f/1024.0f)

__device__ inline u16 h_bits(float f){ union{_Float16 h; u16 s;} u; u.h=(_Float16)f; return u.s; }
__device__ inline float bits_f(u16 s){ union{u16 s2; _Float16 h;} u; u.s2=s; return (float)u.h; }
__device__ inline float sigm(float x){ return 1.f/(1.f+expf(-x)); }

// Coherent 16B A-fragment load: two relaxed agent-scope 8B atomic loads (IF$-served, proven R2..R7).
__device__ inline h8 ldH(const u16* p){
    union{ ull u[2]; h8 v; } t;
    t.u[0]=__hip_atomic_load((const ull*)p,    __ATOMIC_RELAXED, __HIP_MEMORY_SCOPE_AGENT);
    t.u[1]=__hip_atomic_load((const ull*)(p+4),__ATOMIC_RELAXED, __HIP_MEMORY_SCOPE_AGENT);
    return t.v;
}

// ---------------- pre-pack W lo-planes (fp16, x1024), [cg][kg][n 0..32)[8] ----------------
__global__ __launch_bounds__(256) void prepack(const float* __restrict__ W0,
                                               const float* __restrict__ W1,
                                               u16* __restrict__ ws) {
    int idx = blockIdx.x * 256 + threadIdx.x;
    const int NW0 = 64 * 104 * 32;
    if (idx < NW0) {
        int cg  = idx / (104 * 32);
        int rem = idx - cg * (104 * 32);
        int kg = rem >> 5, n = rem & 31;
        int col = ((n >> 3) << 9) + (cg << 3) + (n & 7);
        u16 t[8];
#pragma unroll
        for (int j = 0; j < 8; j++) {
            int k = kg * 8 + j;
            float w = 0.f;
            if (k < 300) w = W0[k * 2048 + col];
            else if (k >= 320) w = W0[(k - 20) * 2048 + col];
            _Float16 wh = (_Float16)w;
            t[j] = h_bits((w - (float)wh) * 1024.0f);
        }
#pragma unroll
        for (int j = 0; j < 8; j++) ws[W0LOFF + (size_t)idx * 8 + j] = t[j];
    } else {
        int i2 = idx - NW0;
        if (i2 < 64 * 128 * 32) {
            int cg  = i2 >> 12;           // / (128*32)
            int rem = i2 & 4095;
            int kg = rem >> 5, n = rem & 31;
            int col = ((n >> 3) << 9) + (cg << 3) + (n & 7);
            u16 t[8];
#pragma unroll
            for (int j = 0; j < 8; j++) {
                float w = W1[(kg * 8 + j) * 2048 + col];
                _Float16 wh = (_Float16)w;
                t[j] = h_bits((w - (float)wh) * 1024.0f);
            }
#pragma unroll
            for (int j = 0; j < 8; j++) ws[W1LOFF + (size_t)i2 * 8 + j] = t[j];
        }
    }
}

// Fence-free split barrier — proven structure (threads 0..255 poll packed flags).
// 256 blocks: thread tid polls flags[tid]. Initial poison (0xAAAAAAAA<0) needs no init.
// s_sleep(4) retained from R3 (proven passing, -2%).
__device__ inline void barrier_arrive(int* __restrict__ flags, int tid, int bid, int target) {
    __builtin_amdgcn_s_waitcnt(0);
    __syncthreads();
    if (tid == 0)
        __hip_atomic_store(flags + bid, target, __ATOMIC_RELAXED, __HIP_MEMORY_SCOPE_AGENT);
}
__device__ inline void barrier_wait(int* __restrict__ flags, int tid, int target) {
    if (tid < 256)
        while (__hip_atomic_load(flags + tid, __ATOMIC_RELAXED, __HIP_MEMORY_SCOPE_AGENT) < target)
            __builtin_amdgcn_s_sleep(4);
    __syncthreads();
}

struct X4 { f4 h0, l0, h1, l1; };

// ---------------- persistent cooperative LSTM kernel ----------------
// grid 256 x 512 (1 block/CU, 8 waves = 2/SIMD): bid = inner*2 + lyr.
//   lyr = bid&1 : 0 -> layer-0 duties, 1 -> layer-1 duties (R7 split, proven)
//   inner = bid>>1 in [0,128): bq = inner>>6 (64-row batch half), cg = inner&63.
// R11 change (TLP, zero reordering): 8 waves per block. mt = wave&3 is the m-tile
//   (16 rows) as before; g2 = wave>>2 splits each wave's former kt range in HALF.
//   Each wave runs the byte-identical interleaved ldH->MFMA structure over its half
//   (disjoint addresses -> coherent volume unchanged), doubling in-flight coherent
//   loads per CU to hide the contended agent-atomic latency via TLP instead of the
//   ILP hoist that broke R8/R9. Partial sums meet in csm[2] planes, summed at the
//   gate read (fp32 reassociation only). Epilogue: 1 cell/thread (512 threads).
__global__ __launch_bounds__(512, 1) void lstm_coop(
    const int* __restrict__ x, const float* __restrict__ emb,
    const float* __restrict__ W0, const float* __restrict__ b0,
    const float* __restrict__ W1, const float* __restrict__ b1,
    const float* __restrict__ Wd, const float* __restrict__ bd,
    float* __restrict__ out, u16* __restrict__ ws) {

    const int tid  = threadIdx.x;
    const int lane = tid & 63;
    const int wave = tid >> 6;        // 0..7
    const int mt   = wave & 3;        // m-tile (16 rows each)
    const int g2   = wave >> 2;       // k-half 0/1
    const int quad = lane >> 4;       // 0..3 : k-chunk of 8 in frags
    const int fm   = lane & 15;       // A: m, B: n, C/D: col
    const int bid  = blockIdx.x;
    const int lyr  = bid & 1;
    const int inner= bid >> 1;
    const int bq   = inner >> 6;
    const int cg   = inner & 63;

    __shared__ u16   whi[128 * 32 * 8];   // 65,536 B (lyr0 uses first 104*32*8)
    __shared__ float csm[2][64 * 33];     // 16,896 B : one plane per k-half

    int* flags = (int*)ws;
    const u16* w0lo = ws + W0LOFF + (size_t)cg * 104 * 32 * 8;   // block-private slice
    const u16* w1lo = ws + W1LOFF + (size_t)cg * 128 * 32 * 8;

    // --- fill LDS hi-plane (fp16) of this block's layer & 32 gate columns, layout [kg][n][8] ---
    if (lyr == 0) {
        for (int i = tid; i < 104 * 32 * 8; i += 512) {
            int kg = i >> 8; int rem = i & 255; int n = rem >> 3; int j = rem & 7;
            int k = kg * 8 + j;
            int col = ((n >> 3) << 9) + (cg << 3) + (n & 7);
            float w = 0.f;
            if (k < 300) w = W0[k * 2048 + col];
            else if (k >= 320) w = W0[(k - 20) * 2048 + col];
            whi[i] = h_bits(w);
        }
    } else {
        for (int i = tid; i < 128 * 32 * 8; i += 512) {
            int kg = i >> 8; int rem = i & 255; int n = rem >> 3; int j = rem & 7;
            int k = kg * 8 + j;
            int col = ((n >> 3) << 9) + (cg << 3) + (n & 7);
            whi[i] = h_bits(W1[k * 2048 + col]);
        }
    }

    // h addressing (frag-major, unchanged layout): plane u16 index = cg*1024 + row*8 + c, c in [0,8)
    // --- zero-init own slice: lyr0 -> h0 parity 0 ; lyr1 -> h1 parity 1 (64 rows x 8 cols) ---
    if (tid < 256) {
        int row = bq * 64 + (tid >> 2);
        int c = (tid & 3) << 1;
        unsigned int* pz = (unsigned int*)(ws + (lyr ? H1OFF + 1 * HPAR : H0OFF + 0 * HPAR)
                                           + cg * 1024 + row * 8 + c);
        __hip_atomic_store(pz, 0u, __ATOMIC_RELAXED, __HIP_MEMORY_SCOPE_AGENT);
    }

    const int arow = bq * 64 + mt * 16 + fm;   // A-frag row (batch index)
    // act cell: ONE cell per thread: (row actm, h-col acthc in [0,8))
    const int actm   = tid >> 3;               // 0..63
    const int acthc  = tid & 7;                // 0..7
    const int actrow = bq * 64 + actm;
    const int ca = (cg << 3) + acthc;          // global h-col of the cell

    const float bi = lyr ? b1[ca]        : b0[ca];
    const float bj = lyr ? b1[512 + ca]  : b0[512 + ca];
    const float bf = lyr ? b1[1024 + ca] : b0[1024 + ca];
    const float bo = lyr ? b1[1536 + ca] : b0[1536 + ca];

    float cs = 0.f;

    // x-part GEMM of layer 0 for timestep pp; this wave's k-half: kt = g2*5 + ktl, ktl 0..4.
    auto xgemm = [&](int pp) -> X4 {
        X4 a; a.h0 = (f4){0,0,0,0}; a.l0 = a.h0; a.h1 = a.h0; a.l1 = a.h0;
        int xi = x[arow * Tt + pp];
        xi = (xi < 0) ? 0 : ((xi >= 50000) ? 49999 : xi);
        const float* embrow = emb + (size_t)xi * 300;
#pragma unroll
        for (int ktl = 0; ktl < 5; ktl++) {
            int kt = g2 * 5 + ktl;
            int kbase = kt * 32 + quad * 8;
            h8 af;
            if (kt < 9) {
                f4 u0 = *(const f4*)(embrow + kbase);
                f4 u1 = *(const f4*)(embrow + kbase + 4);
#pragma unroll
                for (int e = 0; e < 4; e++) { af[e] = (_Float16)u0[e]; af[4+e] = (_Float16)u1[e]; }
            } else {
#pragma unroll
                for (int e = 0; e < 8; e++) { int kk = kbase + e; af[e] = (_Float16)((kk < 300) ? embrow[kk] : 0.f); }
            }
            int kb = (kt * 4 + quad) * 32;
            a.h0 = MFMA(af, *(const h8*)&whi[(kb + fm) * 8],        a.h0, 0,0,0);
            a.l0 = MFMA(af, *(const h8*)(w0lo + (kb + fm) * 8),      a.l0, 0,0,0);
            a.h1 = MFMA(af, *(const h8*)&whi[(kb + 16 + fm) * 8],   a.h1, 0,0,0);
            a.l1 = MFMA(af, *(const h8*)(w0lo + (kb + 16 + fm) * 8), a.l1, 0,0,0);
        }
        return a;
    };

    X4 accx;
    barrier_arrive(flags, tid, bid, 1);
    if (lyr == 0) accx = xgemm(0);
    barrier_wait(flags, tid, 1);

    for (int p = 0; p <= Tt; ++p) {
        const int par = p & 1, wpar = 1 - par;

        if (lyr == 1) {
            if (p >= 1) {   // ---- layer 1 for t=p-1 : g1 = [h0(p-1) | h1(p-2)] @ W1 ----
                f4 aH0 = (f4){0,0,0,0}, aL0 = aH0, aH1 = aH0, aL1 = aH0;
                // waves g2=0 handle the h0 half (kt 0..15), g2=1 the h1 half (kt 16..31)
                const u16* hp = ws + (g2 ? H1OFF : H0OFF) + par * HPAR + arow * 8;
#pragma unroll 8
                for (int ktl = 0; ktl < 16; ktl++) {
                    h8 af = ldH(hp + (ktl * 4 + quad) * 1024);
                    int kb = ((g2 * 16 + ktl) * 4 + quad) * 32;
                    aH0 = MFMA(af, *(const h8*)&whi[(kb + fm) * 8],        aH0, 0,0,0);
                    aL0 = MFMA(af, *(const h8*)(w1lo + (kb + fm) * 8),      aL0, 0,0,0);
                    aH1 = MFMA(af, *(const h8*)&whi[(kb + 16 + fm) * 8],   aH1, 0,0,0);
                    aL1 = MFMA(af, *(const h8*)(w1lo + (kb + 16 + fm) * 8), aL1, 0,0,0);
                }
#pragma unroll
                for (int r = 0; r < 4; r++) {
                    csm[g2][(mt * 16 + quad * 4 + r) * 33 + fm]      = aH0[r] + aL0[r] * LOSC;
                    csm[g2][(mt * 16 + quad * 4 + r) * 33 + 16 + fm] = aH1[r] + aL1[r] * LOSC;
                }
                __syncthreads();
                {   // gates: in-block col = gate*8 + hc ; sum the two k-half planes
                    float gi = csm[0][actm * 33 + acthc]      + csm[1][actm * 33 + acthc]      + bi;
                    float gj = csm[0][actm * 33 + 8 + acthc]  + csm[1][actm * 33 + 8 + acthc]  + bj;
                    float gf = csm[0][actm * 33 + 16 + acthc] + csm[1][actm * 33 + 16 + acthc] + bf;
                    float go = csm[0][actm * 33 + 24 + acthc] + csm[1][actm * 33 + 24 + acthc] + bo;
                    cs = cs * sigm(gf + 1.f) + sigm(gi) * tanhf(gj);
                    float hv = tanhf(cs) * sigm(go);
                    u16 hb = h_bits(hv);
                    unsigned int pa = (unsigned int)hb | (((unsigned int)(u16)__shfl_xor((int)hb, 1, 64)) << 16);
                    if (!(acthc & 1)) {
                        u16* base = ws + H1OFF + wpar * HPAR + cg * 1024 + actrow * 8;
                        __hip_atomic_store((unsigned int*)(base + acthc), pa, __ATOMIC_RELAXED, __HIP_MEMORY_SCOPE_AGENT);
                    }
                }
            }
        } else {
            if (p < Tt) {   // ---- layer 0 h-part for t=p (x-part already in accx) ----
                f4 aH0 = accx.h0, aL0 = accx.l0, aH1 = accx.h1, aL1 = accx.l1;
                const u16* h0p = ws + H0OFF + par * HPAR + arow * 8;
#pragma unroll 8
                for (int ktl = 0; ktl < 8; ktl++) {
                    int kt = 10 + g2 * 8 + ktl;       // kt 10..17 / 18..25
                    h8 af = ldH(h0p + ((kt - 10) * 4 + quad) * 1024);
                    int kb = (kt * 4 + quad) * 32;
                    aH0 = MFMA(af, *(const h8*)&whi[(kb + fm) * 8],        aH0, 0,0,0);
                    aL0 = MFMA(af, *(const h8*)(w0lo + (kb + fm) * 8),      aL0, 0,0,0);
                    aH1 = MFMA(af, *(const h8*)&whi[(kb + 16 + fm) * 8],   aH1, 0,0,0);
                    aL1 = MFMA(af, *(const h8*)(w0lo + (kb + 16 + fm) * 8), aL1, 0,0,0);
                }
#pragma unroll
                for (int r = 0; r < 4; r++) {
                    csm[g2][(mt * 16 + quad * 4 + r) * 33 + fm]      = aH0[r] + aL0[r] * LOSC;
                    csm[g2][(mt * 16 + quad * 4 + r) * 33 + 16 + fm] = aH1[r] + aL1[r] * LOSC;
                }
                __syncthreads();
                {
                    float gi = csm[0][actm * 33 + acthc]      + csm[1][actm * 33 + acthc]      + bi;
                    float gj = csm[0][actm * 33 + 8 + acthc]  + csm[1][actm * 33 + 8 + acthc]  + bj;
                    float gf = csm[0][actm * 33 + 16 + acthc] + csm[1][actm * 33 + 16 + acthc] + bf;
                    float go = csm[0][actm * 33 + 24 + acthc] + csm[1][actm * 33 + 24 + acthc] + bo;
                    cs = cs * sigm(gf + 1.f) + sigm(gi) * tanhf(gj);
                    float hv = tanhf(cs) * sigm(go);
                    u16 hb = h_bits(hv);
                    unsigned int pa = (unsigned int)hb | (((unsigned int)(u16)__shfl_xor((int)hb, 1, 64)) << 16);
                    if (!(acthc & 1)) {
                        u16* base = ws + H0OFF + wpar * HPAR + cg * 1024 + actrow * 8;
                        __hip_atomic_store((unsigned int*)(base + acthc), pa, __ATOMIC_RELAXED, __HIP_MEMORY_SCOPE_AGENT);
                    }
                }
            }
        }

        barrier_arrive(flags, tid, bid, p + 2);
        if (lyr == 0 && p + 1 < Tt) accx = xgemm(p + 1);
        barrier_wait(flags, tid, p + 2);
    }

    // ---- final logits: h1(T-1) lives in parity 1 (frag-major addressing, unchanged) ----
    if (bid == 0 && tid < 256) {
        int b = tid >> 1, jj = tid & 1;
        float sum = bd[jj];
        const u16* hh = ws + H1OFF + 1 * HPAR;
        for (int g = 0; g < 64; g++) {
#pragma unroll
            for (int j4 = 0; j4 < 8; j4 += 4) {
                ull u = __hip_atomic_load((const ull*)(hh + (g * 128 + b) * 8 + j4),
                                          __ATOMIC_RELAXED, __HIP_MEMORY_SCOPE_AGENT);
#pragma unroll
                for (int e = 0; e < 4; e++)
                    sum += bits_f((u16)(u >> (16 * e))) * Wd[(g * 8 + j4 + e) * 2 + jj];
            }
        }
        out[b * 2 + jj] = sum;
    }
}

extern "C" void kernel_launch(void* const* d_in, const int* in_sizes, int n_in,
                              void* d_out, int out_size, void* d_ws, size_t ws_size,
                              hipStream_t stream) {
    const int*   x   = (const int*)d_in[0];
    const float* emb = (const float*)d_in[1];
    const float* W0  = (const float*)d_in[2];
    const float* b0  = (const float*)d_in[3];
    const float* W1  = (const float*)d_in[4];
    const float* b1  = (const float*)d_in[5];
    const float* Wd  = (const float*)d_in[6];
    const float* bd  = (const float*)d_in[7];
    float* out = (float*)d_out;
    u16* ws = (u16*)d_ws;

    hipLaunchKernelGGL(prepack, dim3(1856), dim3(256), 0, stream, W0, W1, ws);

    void* args[] = { (void*)&x, (void*)&emb, (void*)&W0, (void*)&b0, (void*)&W1,
                     (void*)&b1, (void*)&Wd, (void*)&bd, (void*)&out, (void*)&ws };
    hipLaunchCooperativeKernel((void*)lstm_coop, dim3(256), dim3(512), args, 0, stream);
}

// Round 5
// 2594.017 us; speedup vs baseline: 1.6566x; 1.2450x over previous
//
#include <hip/hip_runtime.h>

// Problem constants
#define Tt 256

// ws layout in unsigned shorts (fp16 bit patterns / ints for flags):
//  flags : ints [0..256) arrival flags (4B packed)      [first 1KB of 32KB region]
//  h0 [2 parity][64 g][128 row][8]  fp16 frag-major     [256 KB]   (g = col>>3)
//  h1 same                                              [256 KB]
//  w0lo [64 cg][104 kg][32 n][8]  fp16, lo=(w-fp16(w))*1024, block-private frag-lane order
//  w1lo [64 cg][128 kg][32 n][8]
// total = 4,079,616 shorts = 8,159,232 B (byte-identical to the R5..R7 proven budget)
#define FLAGS_SHORTS 16384
#define H0OFF  16384
#define H1OFF  (H0OFF + 2*64*128*8)
#define W0LOFF (H1OFF + 2*64*128*8)
#define W1LOFF (W0LOFF + 64*104*32*8)
#define HPAR   (64*128*8)            // u16 per parity plane = 65536

typedef _Float16 h8 __attribute__((ext_vector_type(8)));
typedef float    f4 __attribute__((ext_vector_type(4)));
typedef unsigned long long ull;
typedef unsigned short u16;

#define MFMA __builtin_amdgcn_mfma_f32_16x16x32_f16
#define LOSC (1.0f/1024.0f)

__device__ inline u16 h_bits(float f){ union{_Float16 h; u16 s;} u; u.h=(_Float16)f; return u.s; }
__device__ inline float bits_f(u16 s){ union{u16 s2; _Float16 h;} u; u.s2=s; return (float)u.h; }
__device__ inline float sigm(float x){ return 1.f/(1.f+expf(-x)); }

// Coherent 16B A-fragment load: two relaxed agent-scope 8B atomic loads (IF$-served, proven R2..R7).
__device__ inline h8 ldH(const u16* p){
    union{ ull u[2]; h8 v; } t;
    t.u[0]=__hip_atomic_load((const ull*)p,    __ATOMIC_RELAXED, __HIP_MEMORY_SCOPE_AGENT);
    t.u[1]=__hip_atomic_load((const ull*)(p+4),__ATOMIC_RELAXED, __HIP_MEMORY_SCOPE_AGENT);
    return t.v;
}

// ---------------- pre-pack W lo-planes (fp16, x1024), [cg][kg][n 0..32)[8] ----------------
__global__ __launch_bounds__(256) void prepack(const float* __restrict__ W0,
                                               const float* __restrict__ W1,
                                               u16* __restrict__ ws) {
    int idx = blockIdx.x * 256 + threadIdx.x;
    const int NW0 = 64 * 104 * 32;
    if (idx < NW0) {
        int cg  = idx / (104 * 32);
        int rem = idx - cg * (104 * 32);
        int kg = rem >> 5, n = rem & 31;
        int col = ((n >> 3) << 9) + (cg << 3) + (n & 7);
        u16 t[8];
#pragma unroll
        for (int j = 0; j < 8; j++) {
            int k = kg * 8 + j;
            float w = 0.f;
            if (k < 300) w = W0[k * 2048 + col];
            else if (k >= 320) w = W0[(k - 20) * 2048 + col];
            _Float16 wh = (_Float16)w;
            t[j] = h_bits((w - (float)wh) * 1024.0f);
        }
#pragma unroll
        for (int j = 0; j < 8; j++) ws[W0LOFF + (size_t)idx * 8 + j] = t[j];
    } else {
        int i2 = idx - NW0;
        if (i2 < 64 * 128 * 32) {
            int cg  = i2 >> 12;           // / (128*32)
            int rem = i2 & 4095;
            int kg = rem >> 5, n = rem & 31;
            int col = ((n >> 3) << 9) + (cg << 3) + (n & 7);
            u16 t[8];
#pragma unroll
            for (int j = 0; j < 8; j++) {
                float w = W1[(kg * 8 + j) * 2048 + col];
                _Float16 wh = (_Float16)w;
                t[j] = h_bits((w - (float)wh) * 1024.0f);
            }
#pragma unroll
            for (int j = 0; j < 8; j++) ws[W1LOFF + (size_t)i2 * 8 + j] = t[j];
        }
    }
}

// Fence-free split barrier — proven structure (threads 0..255 poll packed flags).
// 256 blocks: thread tid polls flags[tid]. Initial poison (0xAAAAAAAA<0) needs no init.
// s_sleep(4) retained from R3 (proven passing).
__device__ inline void barrier_arrive(int* __restrict__ flags, int tid, int bid, int target) {
    __builtin_amdgcn_s_waitcnt(0);
    __syncthreads();
    if (tid == 0)
        __hip_atomic_store(flags + bid, target, __ATOMIC_RELAXED, __HIP_MEMORY_SCOPE_AGENT);
}
__device__ inline void barrier_wait(int* __restrict__ flags, int tid, int target) {
    if (tid < 256)
        while (__hip_atomic_load(flags + tid, __ATOMIC_RELAXED, __HIP_MEMORY_SCOPE_AGENT) < target)
            __builtin_amdgcn_s_sleep(4);
    __syncthreads();
}

struct X4 { f4 h0, l0, h1, l1; };

// ---------------- persistent cooperative LSTM kernel ----------------
// grid 256 x 1024 (1 block/CU, 16 waves = 4/SIMD): bid = inner*2 + lyr.
//   lyr = bid&1 : 0 -> layer-0 duties, 1 -> layer-1 duties (R7 split, proven)
//   inner = bid>>1 in [0,128): bq = inner>>6 (64-row batch half), cg = inner&63.
// R12 change (TLP x2 again, zero reordering): 16 waves per block. mt = wave&3 is the
//   m-tile (16 rows); g4 = wave>>2 in [0,4) splits each wave's former kt range in
//   QUARTERS. Per-wave program order remains the proven interleaved ldH->MFMA
//   subsequence (disjoint addresses -> coherent volume unchanged); in-flight coherent
//   loads per CU double again. Partial sums meet in csm[4] planes, summed at the gate
//   read (fp32 reassociation only). Model fit R3/R4: phase = F(8.4us) + S(7.8us)/TLP;
//   this tests TLP=4 -> predicted ~10.3-11 us/phase.
__global__ __launch_bounds__(1024, 1) void lstm_coop(
    const int* __restrict__ x, const float* __restrict__ emb,
    const float* __restrict__ W0, const float* __restrict__ b0,
    const float* __restrict__ W1, const float* __restrict__ b1,
    const float* __restrict__ Wd, const float* __restrict__ bd,
    float* __restrict__ out, u16* __restrict__ ws) {

    const int tid  = threadIdx.x;
    const int lane = tid & 63;
    const int wave = tid >> 6;        // 0..15
    const int mt   = wave & 3;        // m-tile (16 rows each)
    const int g4   = wave >> 2;       // k-quarter 0..3
    const int quad = lane >> 4;       // 0..3 : k-chunk of 8 in frags
    const int fm   = lane & 15;       // A: m, B: n, C/D: col
    const int bid  = blockIdx.x;
    const int lyr  = bid & 1;
    const int inner= bid >> 1;
    const int bq   = inner >> 6;
    const int cg   = inner & 63;

    __shared__ u16   whi[128 * 32 * 8];   // 65,536 B (lyr0 uses first 104*32*8)
    __shared__ float csm[4][64 * 33];     // 33,792 B : one plane per k-quarter -> 99,328 B total

    int* flags = (int*)ws;
    const u16* w0lo = ws + W0LOFF + (size_t)cg * 104 * 32 * 8;   // block-private slice
    const u16* w1lo = ws + W1LOFF + (size_t)cg * 128 * 32 * 8;

    // --- fill LDS hi-plane (fp16) of this block's layer & 32 gate columns, layout [kg][n][8] ---
    if (lyr == 0) {
        for (int i = tid; i < 104 * 32 * 8; i += 1024) {
            int kg = i >> 8; int rem = i & 255; int n = rem >> 3; int j = rem & 7;
            int k = kg * 8 + j;
            int col = ((n >> 3) << 9) + (cg << 3) + (n & 7);
            float w = 0.f;
            if (k < 300) w = W0[k * 2048 + col];
            else if (k >= 320) w = W0[(k - 20) * 2048 + col];
            whi[i] = h_bits(w);
        }
    } else {
        for (int i = tid; i < 128 * 32 * 8; i += 1024) {
            int kg = i >> 8; int rem = i & 255; int n = rem >> 3; int j = rem & 7;
            int k = kg * 8 + j;
            int col = ((n >> 3) << 9) + (cg << 3) + (n & 7);
            whi[i] = h_bits(W1[k * 2048 + col]);
        }
    }

    // h addressing (frag-major, unchanged layout): plane u16 index = cg*1024 + row*8 + c, c in [0,8)
    // --- zero-init own slice: lyr0 -> h0 parity 0 ; lyr1 -> h1 parity 1 (64 rows x 8 cols) ---
    if (tid < 256) {
        int row = bq * 64 + (tid >> 2);
        int c = (tid & 3) << 1;
        unsigned int* pz = (unsigned int*)(ws + (lyr ? H1OFF + 1 * HPAR : H0OFF + 0 * HPAR)
                                           + cg * 1024 + row * 8 + c);
        __hip_atomic_store(pz, 0u, __ATOMIC_RELAXED, __HIP_MEMORY_SCOPE_AGENT);
    }

    const int arow = bq * 64 + mt * 16 + fm;   // A-frag row (batch index)
    // act cell: ONE cell per thread for tid<512: (row actm, h-col acthc in [0,8))
    const int actm   = tid >> 3;               // 0..63 valid for tid<512
    const int acthc  = tid & 7;                // 0..7
    const int actrow = bq * 64 + actm;
    const int ca = (cg << 3) + acthc;          // global h-col of the cell

    const float bi = lyr ? b1[ca & 511]        : b0[ca & 511];
    const float bj = lyr ? b1[512 + (ca & 511)]  : b0[512 + (ca & 511)];
    const float bf = lyr ? b1[1024 + (ca & 511)] : b0[1024 + (ca & 511)];
    const float bo = lyr ? b1[1536 + (ca & 511)] : b0[1536 + (ca & 511)];

    float cs = 0.f;

    // x-part GEMM of layer 0 for timestep pp; this wave's k-quarter: kt = ktl*4 + g4 (kt<10).
    auto xgemm = [&](int pp) -> X4 {
        X4 a; a.h0 = (f4){0,0,0,0}; a.l0 = a.h0; a.h1 = a.h0; a.l1 = a.h0;
        int xi = x[arow * Tt + pp];
        xi = (xi < 0) ? 0 : ((xi >= 50000) ? 49999 : xi);
        const float* embrow = emb + (size_t)xi * 300;
#pragma unroll
        for (int ktl = 0; ktl < 3; ktl++) {
            int kt = ktl * 4 + g4;
            if (kt < 10) {
                int kbase = kt * 32 + quad * 8;
                h8 af;
                if (kt < 9) {
                    f4 u0 = *(const f4*)(embrow + kbase);
                    f4 u1 = *(const f4*)(embrow + kbase + 4);
#pragma unroll
                    for (int e = 0; e < 4; e++) { af[e] = (_Float16)u0[e]; af[4+e] = (_Float16)u1[e]; }
                } else {
#pragma unroll
                    for (int e = 0; e < 8; e++) { int kk = kbase + e; af[e] = (_Float16)((kk < 300) ? embrow[kk] : 0.f); }
                }
                int kb = (kt * 4 + quad) * 32;
                a.h0 = MFMA(af, *(const h8*)&whi[(kb + fm) * 8],        a.h0, 0,0,0);
                a.l0 = MFMA(af, *(const h8*)(w0lo + (kb + fm) * 8),      a.l0, 0,0,0);
                a.h1 = MFMA(af, *(const h8*)&whi[(kb + 16 + fm) * 8],   a.h1, 0,0,0);
                a.l1 = MFMA(af, *(const h8*)(w0lo + (kb + 16 + fm) * 8), a.l1, 0,0,0);
            }
        }
        return a;
    };

    X4 accx;
    barrier_arrive(flags, tid, bid, 1);
    if (lyr == 0) accx = xgemm(0);
    barrier_wait(flags, tid, 1);

    for (int p = 0; p <= Tt; ++p) {
        const int par = p & 1, wpar = 1 - par;

        if (lyr == 1) {
            if (p >= 1) {   // ---- layer 1 for t=p-1 : g1 = [h0(p-1) | h1(p-2)] @ W1 ----
                f4 aH0 = (f4){0,0,0,0}, aL0 = aH0, aH1 = aH0, aL1 = aH0;
                // k-quarters: g4 0,1 -> h0 half (kt 0..15); g4 2,3 -> h1 half (kt 16..31)
                const u16* hp = ws + (g4 >= 2 ? H1OFF : H0OFF) + par * HPAR + arow * 8;
                const int ktbase = g4 * 8;                   // global kt base
                const int ltbase = (g4 & 1) * 8;             // local kt within the h half
#pragma unroll
                for (int ktl = 0; ktl < 8; ktl++) {
                    h8 af = ldH(hp + ((ltbase + ktl) * 4 + quad) * 1024);
                    int kb = ((ktbase + ktl) * 4 + quad) * 32;
                    aH0 = MFMA(af, *(const h8*)&whi[(kb + fm) * 8],        aH0, 0,0,0);
                    aL0 = MFMA(af, *(const h8*)(w1lo + (kb + fm) * 8),      aL0, 0,0,0);
                    aH1 = MFMA(af, *(const h8*)&whi[(kb + 16 + fm) * 8],   aH1, 0,0,0);
                    aL1 = MFMA(af, *(const h8*)(w1lo + (kb + 16 + fm) * 8), aL1, 0,0,0);
                }
#pragma unroll
                for (int r = 0; r < 4; r++) {
                    csm[g4][(mt * 16 + quad * 4 + r) * 33 + fm]      = aH0[r] + aL0[r] * LOSC;
                    csm[g4][(mt * 16 + quad * 4 + r) * 33 + 16 + fm] = aH1[r] + aL1[r] * LOSC;
                }
                __syncthreads();
                if (tid < 512) {   // gates: in-block col = gate*8 + hc ; sum the 4 k-quarter planes
                    float gi = csm[0][actm * 33 + acthc]      + csm[1][actm * 33 + acthc]
                             + csm[2][actm * 33 + acthc]      + csm[3][actm * 33 + acthc]      + bi;
                    float gj = csm[0][actm * 33 + 8 + acthc]  + csm[1][actm * 33 + 8 + acthc]
                             + csm[2][actm * 33 + 8 + acthc]  + csm[3][actm * 33 + 8 + acthc]  + bj;
                    float gf = csm[0][actm * 33 + 16 + acthc] + csm[1][actm * 33 + 16 + acthc]
                             + csm[2][actm * 33 + 16 + acthc] + csm[3][actm * 33 + 16 + acthc] + bf;
                    float go = csm[0][actm * 33 + 24 + acthc] + csm[1][actm * 33 + 24 + acthc]
                             + csm[2][actm * 33 + 24 + acthc] + csm[3][actm * 33 + 24 + acthc] + bo;
                    cs = cs * sigm(gf + 1.f) + sigm(gi) * tanhf(gj);
                    float hv = tanhf(cs) * sigm(go);
                    u16 hb = h_bits(hv);
                    unsigned int pa = (unsigned int)hb | (((unsigned int)(u16)__shfl_xor((int)hb, 1, 64)) << 16);
                    if (!(acthc & 1)) {
                        u16* base = ws + H1OFF + wpar * HPAR + cg * 1024 + actrow * 8;
                        __hip_atomic_store((unsigned int*)(base + acthc), pa, __ATOMIC_RELAXED, __HIP_MEMORY_SCOPE_AGENT);
                    }
                }
            }
        } else {
            if (p < Tt) {   // ---- layer 0 h-part for t=p (x-part already in accx) ----
                f4 aH0 = accx.h0, aL0 = accx.l0, aH1 = accx.h1, aL1 = accx.l1;
                const u16* h0p = ws + H0OFF + par * HPAR + arow * 8;
#pragma unroll
                for (int ktl = 0; ktl < 4; ktl++) {
                    int kt = 10 + g4 * 4 + ktl;       // kt 10..25 in quarters
                    h8 af = ldH(h0p + ((kt - 10) * 4 + quad) * 1024);
                    int kb = (kt * 4 + quad) * 32;
                    aH0 = MFMA(af, *(const h8*)&whi[(kb + fm) * 8],        aH0, 0,0,0);
                    aL0 = MFMA(af, *(const h8*)(w0lo + (kb + fm) * 8),      aL0, 0,0,0);
                    aH1 = MFMA(af, *(const h8*)&whi[(kb + 16 + fm) * 8],   aH1, 0,0,0);
                    aL1 = MFMA(af, *(const h8*)(w0lo + (kb + 16 + fm) * 8), aL1, 0,0,0);
                }
#pragma unroll
                for (int r = 0; r < 4; r++) {
                    csm[g4][(mt * 16 + quad * 4 + r) * 33 + fm]      = aH0[r] + aL0[r] * LOSC;
                    csm[g4][(mt * 16 + quad * 4 + r) * 33 + 16 + fm] = aH1[r] + aL1[r] * LOSC;
                }
                __syncthreads();
                if (tid < 512) {
                    float gi = csm[0][actm * 33 + acthc]      + csm[1][actm * 33 + acthc]
                             + csm[2][actm * 33 + acthc]      + csm[3][actm * 33 + acthc]      + bi;
                    float gj = csm[0][actm * 33 + 8 + acthc]  + csm[1][actm * 33 + 8 + acthc]
                             + csm[2][actm * 33 + 8 + acthc]  + csm[3][actm * 33 + 8 + acthc]  + bj;
                    float gf = csm[0][actm * 33 + 16 + acthc] + csm[1][actm * 33 + 16 + acthc]
                             + csm[2][actm * 33 + 16 + acthc] + csm[3][actm * 33 + 16 + acthc] + bf;
                    float go = csm[0][actm * 33 + 24 + acthc] + csm[1][actm * 33 + 24 + acthc]
                             + csm[2][actm * 33 + 24 + acthc] + csm[3][actm * 33 + 24 + acthc] + bo;
                    cs = cs * sigm(gf + 1.f) + sigm(gi) * tanhf(gj);
                    float hv = tanhf(cs) * sigm(go);
                    u16 hb = h_bits(hv);
                    unsigned int pa = (unsigned int)hb | (((unsigned int)(u16)__shfl_xor((int)hb, 1, 64)) << 16);
                    if (!(acthc & 1)) {
                        u16* base = ws + H0OFF + wpar * HPAR + cg * 1024 + actrow * 8;
                        __hip_atomic_store((unsigned int*)(base + acthc), pa, __ATOMIC_RELAXED, __HIP_MEMORY_SCOPE_AGENT);
                    }
                }
            }
        }

        barrier_arrive(flags, tid, bid, p + 2);
        if (lyr == 0 && p + 1 < Tt) accx = xgemm(p + 1);
        barrier_wait(flags, tid, p + 2);
    }

    // ---- final logits: h1(T-1) lives in parity 1 (frag-major addressing, unchanged) ----
    if (bid == 0 && tid < 256) {
        int b = tid >> 1, jj = tid & 1;
        float sum = bd[jj];
        const u16* hh = ws + H1OFF + 1 * HPAR;
        for (int g = 0; g < 64; g++) {
#pragma unroll
            for (int j4 = 0; j4 < 8; j4 += 4) {
                ull u = __hip_atomic_load((const ull*)(hh + (g * 128 + b) * 8 + j4),
                                          __ATOMIC_RELAXED, __HIP_MEMORY_SCOPE_AGENT);
#pragma unroll
                for (int e = 0; e < 4; e++)
                    sum += bits_f((u16)(u >> (16 * e))) * Wd[(g * 8 + j4 + e) * 2 + jj];
            }
        }
        out[b * 2 + jj] = sum;
    }
}

extern "C" void kernel_launch(void* const* d_in, const int* in_sizes, int n_in,
                              void* d_out, int out_size, void* d_ws, size_t ws_size,
                              hipStream_t stream) {
    const int*   x   = (const int*)d_in[0];
    const float* emb = (const float*)d_in[1];
    const float* W0  = (const float*)d_in[2];
    const float* b0  = (const float*)d_in[3];
    const float* W1  = (const float*)d_in[4];
    const float* b1  = (const float*)d_in[5];
    const float* Wd  = (const float*)d_in[6];
    const float* bd  = (const float*)d_in[7];
    float* out = (float*)d_out;
    u16* ws = (u16*)d_ws;

    hipLaunchKernelGGL(prepack, dim3(1856), dim3(256), 0, stream, W0, W1, ws);

    void* args[] = { (void*)&x, (void*)&emb, (void*)&W0, (void*)&b0, (void*)&W1,
                     (void*)&b1, (void*)&Wd, (void*)&bd, (void*)&out, (void*)&ws };
    hipLaunchCooperativeKernel((void*)lstm_coop, dim3(256), dim3(1024), args, 0, stream);
}

// Round 7
// 2233.860 us; speedup vs baseline: 1.9237x; 1.1612x over previous
//
#include <hip/hip_runtime.h>

// Problem constants
#define Tt 256

// ws layout in unsigned shorts (fp16 bit patterns / ints for flags):
//  flags : ints [0..256) arrival flags (4B packed)      [first 1KB of 32KB region]
//  h0 [2 parity][64 g][128 row][8]  fp16 frag-major     [256 KB]   (g = col>>3)
//  h1 same                                              [256 KB]
//  w0lo [64 cg][104 kg][32 n][8]  fp16, lo=(w-fp16(w))*1024, block-private frag-lane order
//  w1lo [64 cg][128 kg][32 n][8]
// total = 4,079,616 shorts = 8,159,232 B (byte-identical to the R5..R7 proven budget)
#define FLAGS_SHORTS 16384
#define H0OFF  16384
#define H1OFF  (H0OFF + 2*64*128*8)
#define W0LOFF (H1OFF + 2*64*128*8)
#define W1LOFF (W0LOFF + 64*104*32*8)
#define HPAR   (64*128*8)            // u16 per parity plane = 65536

typedef _Float16 h8 __attribute__((ext_vector_type(8)));
typedef float    f4 __attribute__((ext_vector_type(4)));
typedef unsigned long long ull;
typedef unsigned short u16;

#define MFMA __builtin_amdgcn_mfma_f32_16x16x32_f16
#define LOSC (1.0f/1024.0f)

__device__ inline u16 h_bits(float f){ union{_Float16 h; u16 s;} u; u.h=(_Float16)f; return u.s; }
__device__ inline float bits_f(u16 s){ union{u16 s2; _Float16 h;} u; u.s2=s; return (float)u.h; }
__device__ inline float sigm(float x){ return 1.f/(1.f+expf(-x)); }

// ---- R14 (=R13 with correct builtin types): single-transaction 16B coherent load ----
// One buffer_load_dwordx4 with SC0|SC1 (aux=17: CPol GLC|SCC -> sc0+sc1 on gfx95x):
// system-scope cache policy, bypasses L1/per-XCD L2, served at the MALL coherence
// point — same mechanism as the previous two 8B agent atomics, in ONE transaction.
// Compiler tracks vmcnt and schedules it like a normal load; the proven interleaved
// load->MFMA structure is unchanged.
__device__ inline __amdgpu_buffer_rsrc_t make_rsrc(const void* base){
    return __builtin_amdgcn_make_buffer_rsrc((void*)base, /*stride*/(short)0,
                                             /*num_records*/0xFFFFFFFFu,
                                             /*flags word3*/0x00020000);
}
__device__ inline h8 ldH(__amdgpu_buffer_rsrc_t rsrc, int u16idx){
    auto d = __builtin_amdgcn_raw_buffer_load_b128(rsrc, u16idx * 2, 0, 17 /*SC0|SC1*/);
    h8 v; __builtin_memcpy(&v, &d, 16);
    return v;
}

// ---------------- pre-pack W lo-planes (fp16, x1024), [cg][kg][n 0..32)[8] ----------------
__global__ __launch_bounds__(256) void prepack(const float* __restrict__ W0,
                                               const float* __restrict__ W1,
                                               u16* __restrict__ ws) {
    int idx = blockIdx.x * 256 + threadIdx.x;
    const int NW0 = 64 * 104 * 32;
    if (idx < NW0) {
        int cg  = idx / (104 * 32);
        int rem = idx - cg * (104 * 32);
        int kg = rem >> 5, n = rem & 31;
        int col = ((n >> 3) << 9) + (cg << 3) + (n & 7);
        u16 t[8];
#pragma unroll
        for (int j = 0; j < 8; j++) {
            int k = kg * 8 + j;
            float w = 0.f;
            if (k < 300) w = W0[k * 2048 + col];
            else if (k >= 320) w = W0[(k - 20) * 2048 + col];
            _Float16 wh = (_Float16)w;
            t[j] = h_bits((w - (float)wh) * 1024.0f);
        }
#pragma unroll
        for (int j = 0; j < 8; j++) ws[W0LOFF + (size_t)idx * 8 + j] = t[j];
    } else {
        int i2 = idx - NW0;
        if (i2 < 64 * 128 * 32) {
            int cg  = i2 >> 12;           // / (128*32)
            int rem = i2 & 4095;
            int kg = rem >> 5, n = rem & 31;
            int col = ((n >> 3) << 9) + (cg << 3) + (n & 7);
            u16 t[8];
#pragma unroll
            for (int j = 0; j < 8; j++) {
                float w = W1[(kg * 8 + j) * 2048 + col];
                _Float16 wh = (_Float16)w;
                t[j] = h_bits((w - (float)wh) * 1024.0f);
            }
#pragma unroll
            for (int j = 0; j < 8; j++) ws[W1LOFF + (size_t)i2 * 8 + j] = t[j];
        }
    }
}

// Fence-free split barrier — proven structure (threads 0..255 poll packed flags).
// 256 blocks: thread tid polls flags[tid]. Initial poison (0xAAAAAAAA<0) needs no init.
// s_sleep(4) retained from R3 (proven passing).
__device__ inline void barrier_arrive(int* __restrict__ flags, int tid, int bid, int target) {
    __builtin_amdgcn_s_waitcnt(0);
    __syncthreads();
    if (tid == 0)
        __hip_atomic_store(flags + bid, target, __ATOMIC_RELAXED, __HIP_MEMORY_SCOPE_AGENT);
}
__device__ inline void barrier_wait(int* __restrict__ flags, int tid, int target) {
    if (tid < 256)
        while (__hip_atomic_load(flags + tid, __ATOMIC_RELAXED, __HIP_MEMORY_SCOPE_AGENT) < target)
            __builtin_amdgcn_s_sleep(4);
    __syncthreads();
}

struct X4 { f4 h0, l0, h1, l1; };

// ---------------- persistent cooperative LSTM kernel ----------------
// grid 256 x 1024 (1 block/CU, 16 waves = 4/SIMD): bid = inner*2 + lyr.
//   lyr = bid&1 : 0 -> layer-0 duties, 1 -> layer-1 duties (R7 split, proven)
//   inner = bid>>1 in [0,128): bq = inner>>6 (64-row batch half), cg = inner&63.
// R12 (proven): 16 waves, g4 = wave>>2 k-quarters, csm[4] partial planes.
// R14 change (single variable): ldH = one buffer_load_dwordx4 SC0|SC1 (16B, 1 MALL
//   transaction) instead of two 8B agent atomics. Theory: phase floor F~8.4us is the
//   MALL 8B-transaction service rate (3M transactions/phase); halving transactions
//   at constant bytes should roughly halve F. Interleave structure unchanged.
__global__ __launch_bounds__(1024, 1) void lstm_coop(
    const int* __restrict__ x, const float* __restrict__ emb,
    const float* __restrict__ W0, const float* __restrict__ b0,
    const float* __restrict__ W1, const float* __restrict__ b1,
    const float* __restrict__ Wd, const float* __restrict__ bd,
    float* __restrict__ out, u16* __restrict__ ws) {

    const int tid  = threadIdx.x;
    const int lane = tid & 63;
    const int wave = tid >> 6;        // 0..15
    const int mt   = wave & 3;        // m-tile (16 rows each)
    const int g4   = wave >> 2;       // k-quarter 0..3
    const int quad = lane >> 4;       // 0..3 : k-chunk of 8 in frags
    const int fm   = lane & 15;       // A: m, B: n, C/D: col
    const int bid  = blockIdx.x;
    const int lyr  = bid & 1;
    const int inner= bid >> 1;
    const int bq   = inner >> 6;
    const int cg   = inner & 63;

    __shared__ u16   whi[128 * 32 * 8];   // 65,536 B (lyr0 uses first 104*32*8)
    __shared__ float csm[4][64 * 33];     // 33,792 B : one plane per k-quarter -> 99,328 B total

    int* flags = (int*)ws;
    const u16* w0lo = ws + W0LOFF + (size_t)cg * 104 * 32 * 8;   // block-private slice
    const u16* w1lo = ws + W1LOFF + (size_t)cg * 128 * 32 * 8;
    const __amdgpu_buffer_rsrc_t rsrc = make_rsrc(ws);           // SRD over the ws arena

    // --- fill LDS hi-plane (fp16) of this block's layer & 32 gate columns, layout [kg][n][8] ---
    if (lyr == 0) {
        for (int i = tid; i < 104 * 32 * 8; i += 1024) {
            int kg = i >> 8; int rem = i & 255; int n = rem >> 3; int j = rem & 7;
            int k = kg * 8 + j;
            int col = ((n >> 3) << 9) + (cg << 3) + (n & 7);
            float w = 0.f;
            if (k < 300) w = W0[k * 2048 + col];
            else if (k >= 320) w = W0[(k - 20) * 2048 + col];
            whi[i] = h_bits(w);
        }
    } else {
        for (int i = tid; i < 128 * 32 * 8; i += 1024) {
            int kg = i >> 8; int rem = i & 255; int n = rem >> 3; int j = rem & 7;
            int k = kg * 8 + j;
            int col = ((n >> 3) << 9) + (cg << 3) + (n & 7);
            whi[i] = h_bits(W1[k * 2048 + col]);
        }
    }

    // h addressing (frag-major, unchanged layout): plane u16 index = cg*1024 + row*8 + c, c in [0,8)
    // --- zero-init own slice: lyr0 -> h0 parity 0 ; lyr1 -> h1 parity 1 (64 rows x 8 cols) ---
    if (tid < 256) {
        int row = bq * 64 + (tid >> 2);
        int c = (tid & 3) << 1;
        unsigned int* pz = (unsigned int*)(ws + (lyr ? H1OFF + 1 * HPAR : H0OFF + 0 * HPAR)
                                           + cg * 1024 + row * 8 + c);
        __hip_atomic_store(pz, 0u, __ATOMIC_RELAXED, __HIP_MEMORY_SCOPE_AGENT);
    }

    const int arow = bq * 64 + mt * 16 + fm;   // A-frag row (batch index)
    // act cell: ONE cell per thread for tid<512: (row actm, h-col acthc in [0,8))
    const int actm   = tid >> 3;               // 0..63 valid for tid<512
    const int acthc  = tid & 7;                // 0..7
    const int actrow = bq * 64 + actm;
    const int ca = (cg << 3) + acthc;          // global h-col of the cell

    const float bi = lyr ? b1[ca & 511]        : b0[ca & 511];
    const float bj = lyr ? b1[512 + (ca & 511)]  : b0[512 + (ca & 511)];
    const float bf = lyr ? b1[1024 + (ca & 511)] : b0[1024 + (ca & 511)];
    const float bo = lyr ? b1[1536 + (ca & 511)] : b0[1536 + (ca & 511)];

    float cs = 0.f;

    // x-part GEMM of layer 0 for timestep pp; this wave's k-quarter: kt = ktl*4 + g4 (kt<10).
    auto xgemm = [&](int pp) -> X4 {
        X4 a; a.h0 = (f4){0,0,0,0}; a.l0 = a.h0; a.h1 = a.h0; a.l1 = a.h0;
        int xi = x[arow * Tt + pp];
        xi = (xi < 0) ? 0 : ((xi >= 50000) ? 49999 : xi);
        const float* embrow = emb + (size_t)xi * 300;
#pragma unroll
        for (int ktl = 0; ktl < 3; ktl++) {
            int kt = ktl * 4 + g4;
            if (kt < 10) {
                int kbase = kt * 32 + quad * 8;
                h8 af;
                if (kt < 9) {
                    f4 u0 = *(const f4*)(embrow + kbase);
                    f4 u1 = *(const f4*)(embrow + kbase + 4);
#pragma unroll
                    for (int e = 0; e < 4; e++) { af[e] = (_Float16)u0[e]; af[4+e] = (_Float16)u1[e]; }
                } else {
#pragma unroll
                    for (int e = 0; e < 8; e++) { int kk = kbase + e; af[e] = (_Float16)((kk < 300) ? embrow[kk] : 0.f); }
                }
                int kb = (kt * 4 + quad) * 32;
                a.h0 = MFMA(af, *(const h8*)&whi[(kb + fm) * 8],        a.h0, 0,0,0);
                a.l0 = MFMA(af, *(const h8*)(w0lo + (kb + fm) * 8),      a.l0, 0,0,0);
                a.h1 = MFMA(af, *(const h8*)&whi[(kb + 16 + fm) * 8],   a.h1, 0,0,0);
                a.l1 = MFMA(af, *(const h8*)(w0lo + (kb + 16 + fm) * 8), a.l1, 0,0,0);
            }
        }
        return a;
    };

    X4 accx;
    barrier_arrive(flags, tid, bid, 1);
    if (lyr == 0) accx = xgemm(0);
    barrier_wait(flags, tid, 1);

    for (int p = 0; p <= Tt; ++p) {
        const int par = p & 1, wpar = 1 - par;

        if (lyr == 1) {
            if (p >= 1) {   // ---- layer 1 for t=p-1 : g1 = [h0(p-1) | h1(p-2)] @ W1 ----
                f4 aH0 = (f4){0,0,0,0}, aL0 = aH0, aH1 = aH0, aL1 = aH0;
                // k-quarters: g4 0,1 -> h0 half (kt 0..15); g4 2,3 -> h1 half (kt 16..31)
                const int hpo = (g4 >= 2 ? H1OFF : H0OFF) + par * HPAR + arow * 8;
                const int ktbase = g4 * 8;                   // global kt base
                const int ltbase = (g4 & 1) * 8;             // local kt within the h half
#pragma unroll
                for (int ktl = 0; ktl < 8; ktl++) {
                    h8 af = ldH(rsrc, hpo + ((ltbase + ktl) * 4 + quad) * 1024);
                    int kb = ((ktbase + ktl) * 4 + quad) * 32;
                    aH0 = MFMA(af, *(const h8*)&whi[(kb + fm) * 8],        aH0, 0,0,0);
                    aL0 = MFMA(af, *(const h8*)(w1lo + (kb + fm) * 8),      aL0, 0,0,0);
                    aH1 = MFMA(af, *(const h8*)&whi[(kb + 16 + fm) * 8],   aH1, 0,0,0);
                    aL1 = MFMA(af, *(const h8*)(w1lo + (kb + 16 + fm) * 8), aL1, 0,0,0);
                }
#pragma unroll
                for (int r = 0; r < 4; r++) {
                    csm[g4][(mt * 16 + quad * 4 + r) * 33 + fm]      = aH0[r] + aL0[r] * LOSC;
                    csm[g4][(mt * 16 + quad * 4 + r) * 33 + 16 + fm] = aH1[r] + aL1[r] * LOSC;
                }
                __syncthreads();
                if (tid < 512) {   // gates: in-block col = gate*8 + hc ; sum the 4 k-quarter planes
                    float gi = csm[0][actm * 33 + acthc]      + csm[1][actm * 33 + acthc]
                             + csm[2][actm * 33 + acthc]      + csm[3][actm * 33 + acthc]      + bi;
                    float gj = csm[0][actm * 33 + 8 + acthc]  + csm[1][actm * 33 + 8 + acthc]
                             + csm[2][actm * 33 + 8 + acthc]  + csm[3][actm * 33 + 8 + acthc]  + bj;
                    float gf = csm[0][actm * 33 + 16 + acthc] + csm[1][actm * 33 + 16 + acthc]
                             + csm[2][actm * 33 + 16 + acthc] + csm[3][actm * 33 + 16 + acthc] + bf;
                    float go = csm[0][actm * 33 + 24 + acthc] + csm[1][actm * 33 + 24 + acthc]
                             + csm[2][actm * 33 + 24 + acthc] + csm[3][actm * 33 + 24 + acthc] + bo;
                    cs = cs * sigm(gf + 1.f) + sigm(gi) * tanhf(gj);
                    float hv = tanhf(cs) * sigm(go);
                    u16 hb = h_bits(hv);
                    unsigned int pa = (unsigned int)hb | (((unsigned int)(u16)__shfl_xor((int)hb, 1, 64)) << 16);
                    if (!(acthc & 1)) {
                        u16* base = ws + H1OFF + wpar * HPAR + cg * 1024 + actrow * 8;
                        __hip_atomic_store((unsigned int*)(base + acthc), pa, __ATOMIC_RELAXED, __HIP_MEMORY_SCOPE_AGENT);
                    }
                }
            }
        } else {
            if (p < Tt) {   // ---- layer 0 h-part for t=p (x-part already in accx) ----
                f4 aH0 = accx.h0, aL0 = accx.l0, aH1 = accx.h1, aL1 = accx.l1;
                const int h0o = H0OFF + par * HPAR + arow * 8;
#pragma unroll
                for (int ktl = 0; ktl < 4; ktl++) {
                    int kt = 10 + g4 * 4 + ktl;       // kt 10..25 in quarters
                    h8 af = ldH(rsrc, h0o + ((kt - 10) * 4 + quad) * 1024);
                    int kb = (kt * 4 + quad) * 32;
                    aH0 = MFMA(af, *(const h8*)&whi[(kb + fm) * 8],        aH0, 0,0,0);
                    aL0 = MFMA(af, *(const h8*)(w0lo + (kb + fm) * 8),      aL0, 0,0,0);
                    aH1 = MFMA(af, *(const h8*)&whi[(kb + 16 + fm) * 8],   aH1, 0,0,0);
                    aL1 = MFMA(af, *(const h8*)(w0lo + (kb + 16 + fm) * 8), aL1, 0,0,0);
                }
#pragma unroll
                for (int r = 0; r < 4; r++) {
                    csm[g4][(mt * 16 + quad * 4 + r) * 33 + fm]      = aH0[r] + aL0[r] * LOSC;
                    csm[g4][(mt * 16 + quad * 4 + r) * 33 + 16 + fm] = aH1[r] + aL1[r] * LOSC;
                }
                __syncthreads();
                if (tid < 512) {
                    float gi = csm[0][actm * 33 + acthc]      + csm[1][actm * 33 + acthc]
                             + csm[2][actm * 33 + acthc]      + csm[3][actm * 33 + acthc]      + bi;
                    float gj = csm[0][actm * 33 + 8 + acthc]  + csm[1][actm * 33 + 8 + acthc]
                             + csm[2][actm * 33 + 8 + acthc]  + csm[3][actm * 33 + 8 + acthc]  + bj;
                    float gf = csm[0][actm * 33 + 16 + acthc] + csm[1][actm * 33 + 16 + acthc]
                             + csm[2][actm * 33 + 16 + acthc] + csm[3][actm * 33 + 16 + acthc] + bf;
                    float go = csm[0][actm * 33 + 24 + acthc] + csm[1][actm * 33 + 24 + acthc]
                             + csm[2][actm * 33 + 24 + acthc] + csm[3][actm * 33 + 24 + acthc] + bo;
                    cs = cs * sigm(gf + 1.f) + sigm(gi) * tanhf(gj);
                    float hv = tanhf(cs) * sigm(go);
                    u16 hb = h_bits(hv);
                    unsigned int pa = (unsigned int)hb | (((unsigned int)(u16)__shfl_xor((int)hb, 1, 64)) << 16);
                    if (!(acthc & 1)) {
                        u16* base = ws + H0OFF + wpar * HPAR + cg * 1024 + actrow * 8;
                        __hip_atomic_store((unsigned int*)(base + acthc), pa, __ATOMIC_RELAXED, __HIP_MEMORY_SCOPE_AGENT);
                    }
                }
            }
        }

        barrier_arrive(flags, tid, bid, p + 2);
        if (lyr == 0 && p + 1 < Tt) accx = xgemm(p + 1);
        barrier_wait(flags, tid, p + 2);
    }

    // ---- final logits: h1(T-1) lives in parity 1 (frag-major addressing, unchanged) ----
    if (bid == 0 && tid < 256) {
        int b = tid >> 1, jj = tid & 1;
        float sum = bd[jj];
        const u16* hh = ws + H1OFF + 1 * HPAR;
        for (int g = 0; g < 64; g++) {
#pragma unroll
            for (int j4 = 0; j4 < 8; j4 += 4) {
                ull u = __hip_atomic_load((const ull*)(hh + (g * 128 + b) * 8 + j4),
                                          __ATOMIC_RELAXED, __HIP_MEMORY_SCOPE_AGENT);
#pragma unroll
                for (int e = 0; e < 4; e++)
                    sum += bits_f((u16)(u >> (16 * e))) * Wd[(g * 8 + j4 + e) * 2 + jj];
            }
        }
        out[b * 2 + jj] = sum;
    }
}

extern "C" void kernel_launch(void* const* d_in, const int* in_sizes, int n_in,
                              void* d_out, int out_size, void* d_ws, size_t ws_size,
                              hipStream_t stream) {
    const int*   x   = (const int*)d_in[0];
    const float* emb = (const float*)d_in[1];
    const float* W0  = (const float*)d_in[2];
    const float* b0  = (const float*)d_in[3];
    const float* W1  = (const float*)d_in[4];
    const float* b1  = (const float*)d_in[5];
    const float* Wd  = (const float*)d_in[6];
    const float* bd  = (const float*)d_in[7];
    float* out = (float*)d_out;
    u16* ws = (u16*)d_ws;

    hipLaunchKernelGGL(prepack, dim3(1856), dim3(256), 0, stream, W0, W1, ws);

    void* args[] = { (void*)&x, (void*)&emb, (void*)&W0, (void*)&b0, (void*)&W1,
                     (void*)&b1, (void*)&Wd, (void*)&bd, (void*)&out, (void*)&ws };
    hipLaunchCooperativeKernel((void*)lstm_coop, dim3(256), dim3(1024), args, 0, stream);
}

// Round 8
// 2168.558 us; speedup vs baseline: 1.9816x; 1.0301x over previous
//
#include <hip/hip_runtime.h>

// Problem constants
#define Tt 256

// ws layout in unsigned shorts (fp16 bit patterns / ints for flags):
//  flags : ints [0..256) arrival flags (4B packed)      [first 1KB of 32KB region]
//  h0 [2 parity][64 g][128 row][8]  fp16 frag-major     [256 KB]   (g = col>>3)
//  h1 same                                              [256 KB]
//  w0lo [64 cg][104 kg][32 n][8]  fp16, lo=(w-fp16(w))*1024, block-private frag-lane order
//  w1lo [64 cg][128 kg][32 n][8]
// total = 4,079,616 shorts = 8,159,232 B (byte-identical to the R5..R7 proven budget)
#define FLAGS_SHORTS 16384
#define H0OFF  16384
#define H1OFF  (H0OFF + 2*64*128*8)
#define W0LOFF (H1OFF + 2*64*128*8)
#define W1LOFF (W0LOFF + 64*104*32*8)
#define HPAR   (64*128*8)            // u16 per parity plane = 65536

typedef _Float16 h8 __attribute__((ext_vector_type(8)));
typedef float    f4 __attribute__((ext_vector_type(4)));
typedef unsigned long long ull;
typedef unsigned short u16;

#define MFMA __builtin_amdgcn_mfma_f32_16x16x32_f16
#define LOSC (1.0f/1024.0f)

__device__ inline u16 h_bits(float f){ union{_Float16 h; u16 s;} u; u.h=(_Float16)f; return u.s; }
__device__ inline float bits_f(u16 s){ union{u16 s2; _Float16 h;} u; u.s2=s; return (float)u.h; }
__device__ inline float sigm(float x){ return 1.f/(1.f+expf(-x)); }

// ---- R14 (proven): single-transaction 16B coherent load ----
// One buffer_load_dwordx4 with SC0|SC1 (aux=17): system-scope cache policy, bypasses
// L1/per-XCD L2, served at the MALL coherence point. Ordinary load: vmcnt-tracked,
// ordered against the phase barrier by __syncthreads (workgroup fence + backend
// scheduling barrier) — NOT subject to the R8/R9 relaxed-atomic migration hazard.
__device__ inline __amdgpu_buffer_rsrc_t make_rsrc(const void* base){
    return __builtin_amdgcn_make_buffer_rsrc((void*)base, /*stride*/(short)0,
                                             /*num_records*/0xFFFFFFFFu,
                                             /*flags word3*/0x00020000);
}
__device__ inline h8 ldH(__amdgpu_buffer_rsrc_t rsrc, int u16idx){
    auto d = __builtin_amdgcn_raw_buffer_load_b128(rsrc, u16idx * 2, 0, 17 /*SC0|SC1*/);
    h8 v; __builtin_memcpy(&v, &d, 16);
    return v;
}

// ---------------- pre-pack W lo-planes (fp16, x1024), [cg][kg][n 0..32)[8] ----------------
__global__ __launch_bounds__(256) void prepack(const float* __restrict__ W0,
                                               const float* __restrict__ W1,
                                               u16* __restrict__ ws) {
    int idx = blockIdx.x * 256 + threadIdx.x;
    const int NW0 = 64 * 104 * 32;
    if (idx < NW0) {
        int cg  = idx / (104 * 32);
        int rem = idx - cg * (104 * 32);
        int kg = rem >> 5, n = rem & 31;
        int col = ((n >> 3) << 9) + (cg << 3) + (n & 7);
        u16 t[8];
#pragma unroll
        for (int j = 0; j < 8; j++) {
            int k = kg * 8 + j;
            float w = 0.f;
            if (k < 300) w = W0[k * 2048 + col];
            else if (k >= 320) w = W0[(k - 20) * 2048 + col];
            _Float16 wh = (_Float16)w;
            t[j] = h_bits((w - (float)wh) * 1024.0f);
        }
#pragma unroll
        for (int j = 0; j < 8; j++) ws[W0LOFF + (size_t)idx * 8 + j] = t[j];
    } else {
        int i2 = idx - NW0;
        if (i2 < 64 * 128 * 32) {
            int cg  = i2 >> 12;           // / (128*32)
            int rem = i2 & 4095;
            int kg = rem >> 5, n = rem & 31;
            int col = ((n >> 3) << 9) + (cg << 3) + (n & 7);
            u16 t[8];
#pragma unroll
            for (int j = 0; j < 8; j++) {
                float w = W1[(kg * 8 + j) * 2048 + col];
                _Float16 wh = (_Float16)w;
                t[j] = h_bits((w - (float)wh) * 1024.0f);
            }
#pragma unroll
            for (int j = 0; j < 8; j++) ws[W1LOFF + (size_t)i2 * 8 + j] = t[j];
        }
    }
}

// Fence-free split barrier — proven structure (threads 0..255 poll packed flags).
// 256 blocks: thread tid polls flags[tid]. Initial poison (0xAAAAAAAA<0) needs no init.
// s_sleep(4) retained from R3 (proven passing).
__device__ inline void barrier_arrive(int* __restrict__ flags, int tid, int bid, int target) {
    __builtin_amdgcn_s_waitcnt(0);
    __syncthreads();
    if (tid == 0)
        __hip_atomic_store(flags + bid, target, __ATOMIC_RELAXED, __HIP_MEMORY_SCOPE_AGENT);
}
__device__ inline void barrier_wait(int* __restrict__ flags, int tid, int target) {
    if (tid < 256)
        while (__hip_atomic_load(flags + tid, __ATOMIC_RELAXED, __HIP_MEMORY_SCOPE_AGENT) < target)
            __builtin_amdgcn_s_sleep(4);
    __syncthreads();
}

struct X4 { f4 h0, l0, h1, l1; };

// ---------------- persistent cooperative LSTM kernel ----------------
// grid 256 x 1024 (1 block/CU, 16 waves = 4/SIMD): bid = inner*2 + lyr.
//   lyr = bid&1 : 0 -> layer-0 duties, 1 -> layer-1 duties (R7 split, proven)
//   inner = bid>>1 in [0,128): bq = inner>>6 (64-row batch half), cg = inner&63.
// R12 (proven): 16 waves, g4 = wave>>2 k-quarters, csm[4] partial planes.
// R14 (proven): 16B SC0|SC1 buffer loads (1 MALL transaction per A-frag).
// R15 change (single variable): batch-issue the per-phase coherent loads into a
//   fully-unrolled af[] register array BEFORE the MFMA chain (still strictly after
//   barrier_wait's __syncthreads, one load per address). With VGPR=64 the compiler
//   kept only ~2 loads in flight -> ~6-8 serial MALL round-trips/phase; batching
//   pays the latency ~once. Legal now (ordinary loads + syncthreads ordering) where
//   R8/R9's relaxed-atomic hoist was not.
__global__ __launch_bounds__(1024, 1) void lstm_coop(
    const int* __restrict__ x, const float* __restrict__ emb,
    const float* __restrict__ W0, const float* __restrict__ b0,
    const float* __restrict__ W1, const float* __restrict__ b1,
    const float* __restrict__ Wd, const float* __restrict__ bd,
    float* __restrict__ out, u16* __restrict__ ws) {

    const int tid  = threadIdx.x;
    const int lane = tid & 63;
    const int wave = tid >> 6;        // 0..15
    const int mt   = wave & 3;        // m-tile (16 rows each)
    const int g4   = wave >> 2;       // k-quarter 0..3
    const int quad = lane >> 4;       // 0..3 : k-chunk of 8 in frags
    const int fm   = lane & 15;       // A: m, B: n, C/D: col
    const int bid  = blockIdx.x;
    const int lyr  = bid & 1;
    const int inner= bid >> 1;
    const int bq   = inner >> 6;
    const int cg   = inner & 63;

    __shared__ u16   whi[128 * 32 * 8];   // 65,536 B (lyr0 uses first 104*32*8)
    __shared__ float csm[4][64 * 33];     // 33,792 B : one plane per k-quarter -> 99,328 B total

    int* flags = (int*)ws;
    const u16* w0lo = ws + W0LOFF + (size_t)cg * 104 * 32 * 8;   // block-private slice
    const u16* w1lo = ws + W1LOFF + (size_t)cg * 128 * 32 * 8;
    const __amdgpu_buffer_rsrc_t rsrc = make_rsrc(ws);           // SRD over the ws arena

    // --- fill LDS hi-plane (fp16) of this block's layer & 32 gate columns, layout [kg][n][8] ---
    if (lyr == 0) {
        for (int i = tid; i < 104 * 32 * 8; i += 1024) {
            int kg = i >> 8; int rem = i & 255; int n = rem >> 3; int j = rem & 7;
            int k = kg * 8 + j;
            int col = ((n >> 3) << 9) + (cg << 3) + (n & 7);
            float w = 0.f;
            if (k < 300) w = W0[k * 2048 + col];
            else if (k >= 320) w = W0[(k - 20) * 2048 + col];
            whi[i] = h_bits(w);
        }
    } else {
        for (int i = tid; i < 128 * 32 * 8; i += 1024) {
            int kg = i >> 8; int rem = i & 255; int n = rem >> 3; int j = rem & 7;
            int k = kg * 8 + j;
            int col = ((n >> 3) << 9) + (cg << 3) + (n & 7);
            whi[i] = h_bits(W1[k * 2048 + col]);
        }
    }

    // h addressing (frag-major, unchanged layout): plane u16 index = cg*1024 + row*8 + c, c in [0,8)
    // --- zero-init own slice: lyr0 -> h0 parity 0 ; lyr1 -> h1 parity 1 (64 rows x 8 cols) ---
    if (tid < 256) {
        int row = bq * 64 + (tid >> 2);
        int c = (tid & 3) << 1;
        unsigned int* pz = (unsigned int*)(ws + (lyr ? H1OFF + 1 * HPAR : H0OFF + 0 * HPAR)
                                           + cg * 1024 + row * 8 + c);
        __hip_atomic_store(pz, 0u, __ATOMIC_RELAXED, __HIP_MEMORY_SCOPE_AGENT);
    }

    const int arow = bq * 64 + mt * 16 + fm;   // A-frag row (batch index)
    // act cell: ONE cell per thread for tid<512: (row actm, h-col acthc in [0,8))
    const int actm   = tid >> 3;               // 0..63 valid for tid<512
    const int acthc  = tid & 7;                // 0..7
    const int actrow = bq * 64 + actm;
    const int ca = (cg << 3) + acthc;          // global h-col of the cell

    const float bi = lyr ? b1[ca & 511]        : b0[ca & 511];
    const float bj = lyr ? b1[512 + (ca & 511)]  : b0[512 + (ca & 511)];
    const float bf = lyr ? b1[1024 + (ca & 511)] : b0[1024 + (ca & 511)];
    const float bo = lyr ? b1[1536 + (ca & 511)] : b0[1536 + (ca & 511)];

    float cs = 0.f;

    // x-part GEMM of layer 0 for timestep pp; this wave's k-quarter: kt = ktl*4 + g4 (kt<10).
    auto xgemm = [&](int pp) -> X4 {
        X4 a; a.h0 = (f4){0,0,0,0}; a.l0 = a.h0; a.h1 = a.h0; a.l1 = a.h0;
        int xi = x[arow * Tt + pp];
        xi = (xi < 0) ? 0 : ((xi >= 50000) ? 49999 : xi);
        const float* embrow = emb + (size_t)xi * 300;
#pragma unroll
        for (int ktl = 0; ktl < 3; ktl++) {
            int kt = ktl * 4 + g4;
            if (kt < 10) {
                int kbase = kt * 32 + quad * 8;
                h8 af;
                if (kt < 9) {
                    f4 u0 = *(const f4*)(embrow + kbase);
                    f4 u1 = *(const f4*)(embrow + kbase + 4);
#pragma unroll
                    for (int e = 0; e < 4; e++) { af[e] = (_Float16)u0[e]; af[4+e] = (_Float16)u1[e]; }
                } else {
#pragma unroll
                    for (int e = 0; e < 8; e++) { int kk = kbase + e; af[e] = (_Float16)((kk < 300) ? embrow[kk] : 0.f); }
                }
                int kb = (kt * 4 + quad) * 32;
                a.h0 = MFMA(af, *(const h8*)&whi[(kb + fm) * 8],        a.h0, 0,0,0);
                a.l0 = MFMA(af, *(const h8*)(w0lo + (kb + fm) * 8),      a.l0, 0,0,0);
                a.h1 = MFMA(af, *(const h8*)&whi[(kb + 16 + fm) * 8],   a.h1, 0,0,0);
                a.l1 = MFMA(af, *(const h8*)(w0lo + (kb + 16 + fm) * 8), a.l1, 0,0,0);
            }
        }
        return a;
    };

    X4 accx;
    barrier_arrive(flags, tid, bid, 1);
    if (lyr == 0) accx = xgemm(0);
    barrier_wait(flags, tid, 1);

    for (int p = 0; p <= Tt; ++p) {
        const int par = p & 1, wpar = 1 - par;

        if (lyr == 1) {
            if (p >= 1) {   // ---- layer 1 for t=p-1 : g1 = [h0(p-1) | h1(p-2)] @ W1 ----
                f4 aH0 = (f4){0,0,0,0}, aL0 = aH0, aH1 = aH0, aL1 = aH0;
                // k-quarters: g4 0,1 -> h0 half (kt 0..15); g4 2,3 -> h1 half (kt 16..31)
                const int hpo = (g4 >= 2 ? H1OFF : H0OFF) + par * HPAR + arow * 8;
                const int ktbase = g4 * 8;                   // global kt base
                const int ltbase = (g4 & 1) * 8;             // local kt within the h half
                // R15: batch-issue all 8 coherent loads (after the barrier, before MFMA)
                h8 af[8];
#pragma unroll
                for (int ktl = 0; ktl < 8; ktl++)
                    af[ktl] = ldH(rsrc, hpo + ((ltbase + ktl) * 4 + quad) * 1024);
#pragma unroll
                for (int ktl = 0; ktl < 8; ktl++) {
                    int kb = ((ktbase + ktl) * 4 + quad) * 32;
                    aH0 = MFMA(af[ktl], *(const h8*)&whi[(kb + fm) * 8],        aH0, 0,0,0);
                    aL0 = MFMA(af[ktl], *(const h8*)(w1lo + (kb + fm) * 8),      aL0, 0,0,0);
                    aH1 = MFMA(af[ktl], *(const h8*)&whi[(kb + 16 + fm) * 8],   aH1, 0,0,0);
                    aL1 = MFMA(af[ktl], *(const h8*)(w1lo + (kb + 16 + fm) * 8), aL1, 0,0,0);
                }
#pragma unroll
                for (int r = 0; r < 4; r++) {
                    csm[g4][(mt * 16 + quad * 4 + r) * 33 + fm]      = aH0[r] + aL0[r] * LOSC;
                    csm[g4][(mt * 16 + quad * 4 + r) * 33 + 16 + fm] = aH1[r] + aL1[r] * LOSC;
                }
                __syncthreads();
                if (tid < 512) {   // gates: in-block col = gate*8 + hc ; sum the 4 k-quarter planes
                    float gi = csm[0][actm * 33 + acthc]      + csm[1][actm * 33 + acthc]
                             + csm[2][actm * 33 + acthc]      + csm[3][actm * 33 + acthc]      + bi;
                    float gj = csm[0][actm * 33 + 8 + acthc]  + csm[1][actm * 33 + 8 + acthc]
                             + csm[2][actm * 33 + 8 + acthc]  + csm[3][actm * 33 + 8 + acthc]  + bj;
                    float gf = csm[0][actm * 33 + 16 + acthc] + csm[1][actm * 33 + 16 + acthc]
                             + csm[2][actm * 33 + 16 + acthc] + csm[3][actm * 33 + 16 + acthc] + bf;
                    float go = csm[0][actm * 33 + 24 + acthc] + csm[1][actm * 33 + 24 + acthc]
                             + csm[2][actm * 33 + 24 + acthc] + csm[3][actm * 33 + 24 + acthc] + bo;
                    cs = cs * sigm(gf + 1.f) + sigm(gi) * tanhf(gj);
                    float hv = tanhf(cs) * sigm(go);
                    u16 hb = h_bits(hv);
                    unsigned int pa = (unsigned int)hb | (((unsigned int)(u16)__shfl_xor((int)hb, 1, 64)) << 16);
                    if (!(acthc & 1)) {
                        u16* base = ws + H1OFF + wpar * HPAR + cg * 1024 + actrow * 8;
                        __hip_atomic_store((unsigned int*)(base + acthc), pa, __ATOMIC_RELAXED, __HIP_MEMORY_SCOPE_AGENT);
                    }
                }
            }
        } else {
            if (p < Tt) {   // ---- layer 0 h-part for t=p (x-part already in accx) ----
                f4 aH0 = accx.h0, aL0 = accx.l0, aH1 = accx.h1, aL1 = accx.l1;
                const int h0o = H0OFF + par * HPAR + arow * 8;
                // R15: batch-issue all 4 coherent loads
                h8 af[4];
#pragma unroll
                for (int ktl = 0; ktl < 4; ktl++) {
                    int kt = 10 + g4 * 4 + ktl;       // kt 10..25 in quarters
                    af[ktl] = ldH(rsrc, h0o + ((kt - 10) * 4 + quad) * 1024);
                }
#pragma unroll
                for (int ktl = 0; ktl < 4; ktl++) {
                    int kt = 10 + g4 * 4 + ktl;
                    int kb = (kt * 4 + quad) * 32;
                    aH0 = MFMA(af[ktl], *(const h8*)&whi[(kb + fm) * 8],        aH0, 0,0,0);
                    aL0 = MFMA(af[ktl], *(const h8*)(w0lo + (kb + fm) * 8),      aL0, 0,0,0);
                    aH1 = MFMA(af[ktl], *(const h8*)&whi[(kb + 16 + fm) * 8],   aH1, 0,0,0);
                    aL1 = MFMA(af[ktl], *(const h8*)(w0lo + (kb + 16 + fm) * 8), aL1, 0,0,0);
                }
#pragma unroll
                for (int r = 0; r < 4; r++) {
                    csm[g4][(mt * 16 + quad * 4 + r) * 33 + fm]      = aH0[r] + aL0[r] * LOSC;
                    csm[g4][(mt * 16 + quad * 4 + r) * 33 + 16 + fm] = aH1[r] + aL1[r] * LOSC;
                }
                __syncthreads();
                if (tid < 512) {
                    float gi = csm[0][actm * 33 + acthc]      + csm[1][actm * 33 + acthc]
                             + csm[2][actm * 33 + acthc]      + csm[3][actm * 33 + acthc]      + bi;
                    float gj = csm[0][actm * 33 + 8 + acthc]  + csm[1][actm * 33 + 8 + acthc]
                             + csm[2][actm * 33 + 8 + acthc]  + csm[3][actm * 33 + 8 + acthc]  + bj;
                    float gf = csm[0][actm * 33 + 16 + acthc] + csm[1][actm * 33 + 16 + acthc]
                             + csm[2][actm * 33 + 16 + acthc] + csm[3][actm * 33 + 16 + acthc] + bf;
                    float go = csm[0][actm * 33 + 24 + acthc] + csm[1][actm * 33 + 24 + acthc]
                             + csm[2][actm * 33 + 24 + acthc] + csm[3][actm * 33 + 24 + acthc] + bo;
                    cs = cs * sigm(gf + 1.f) + sigm(gi) * tanhf(gj);
                    float hv = tanhf(cs) * sigm(go);
                    u16 hb = h_bits(hv);
                    unsigned int pa = (unsigned int)hb | (((unsigned int)(u16)__shfl_xor((int)hb, 1, 64)) << 16);
                    if (!(acthc & 1)) {
                        u16* base = ws + H0OFF + wpar * HPAR + cg * 1024 + actrow * 8;
                        __hip_atomic_store((unsigned int*)(base + acthc), pa, __ATOMIC_RELAXED, __HIP_MEMORY_SCOPE_AGENT);
                    }
                }
            }
        }

        barrier_arrive(flags, tid, bid, p + 2);
        if (lyr == 0 && p + 1 < Tt) accx = xgemm(p + 1);
        barrier_wait(flags, tid, p + 2);
    }

    // ---- final logits: h1(T-1) lives in parity 1 (frag-major addressing, unchanged) ----
    if (bid == 0 && tid < 256) {
        int b = tid >> 1, jj = tid & 1;
        float sum = bd[jj];
        const u16* hh = ws + H1OFF + 1 * HPAR;
        for (int g = 0; g < 64; g++) {
#pragma unroll
            for (int j4 = 0; j4 < 8; j4 += 4) {
                ull u = __hip_atomic_load((const ull*)(hh + (g * 128 + b) * 8 + j4),
                                          __ATOMIC_RELAXED, __HIP_MEMORY_SCOPE_AGENT);
#pragma unroll
                for (int e = 0; e < 4; e++)
                    sum += bits_f((u16)(u >> (16 * e))) * Wd[(g * 8 + j4 + e) * 2 + jj];
            }
        }
        out[b * 2 + jj] = sum;
    }
}

extern "C" void kernel_launch(void* const* d_in, const int* in_sizes, int n_in,
                              void* d_out, int out_size, void* d_ws, size_t ws_size,
                              hipStream_t stream) {
    const int*   x   = (const int*)d_in[0];
    const float* emb = (const float*)d_in[1];
    const float* W0  = (const float*)d_in[2];
    const float* b0  = (const float*)d_in[3];
    const float* W1  = (const float*)d_in[4];
    const float* b1  = (const float*)d_in[5];
    const float* Wd  = (const float*)d_in[6];
    const float* bd  = (const float*)d_in[7];
    float* out = (float*)d_out;
    u16* ws = (u16*)d_ws;

    hipLaunchKernelGGL(prepack, dim3(1856), dim3(256), 0, stream, W0, W1, ws);

    void* args[] = { (void*)&x, (void*)&emb, (void*)&W0, (void*)&b0, (void*)&W1,
                     (void*)&b1, (void*)&Wd, (void*)&bd, (void*)&out, (void*)&ws };
    hipLaunchCooperativeKernel((void*)lstm_coop, dim3(256), dim3(1024), args, 0, stream);
}